// Round 15
// baseline (371.495 us; speedup 1.0000x reference)
//
#include <hip/hip_runtime.h>

typedef unsigned short u16;
typedef unsigned int u32;

#define B_ 4
#define S_ 1024
#define D_ 1024
#define H_ 16
#define DH_ 64
#define FF_ 4096
#define M_ 4096
#define SCALE_ 0.125f

typedef __attribute__((ext_vector_type(8))) __bf16 bf16x8;
typedef __attribute__((ext_vector_type(4))) float f32x4;

__device__ __forceinline__ f32x4 mfma16(bf16x8 a, bf16x8 b, f32x4 c) {
  return __builtin_amdgcn_mfma_f32_16x16x32_bf16(a, b, c, 0, 0, 0);
}

// native converts -> compiler emits v_cvt_pk_bf16_f32 (catalog m240)
__device__ __forceinline__ u16 f2bf(float x) {
  union { __bf16 h; u16 u; } cv; cv.h = (__bf16)x; return cv.u;
}
__device__ __forceinline__ float bf2f(u16 u) {
  union { u32 u; float f; } cv; cv.u = ((u32)u) << 16; return cv.f;
}
__device__ __forceinline__ u32 packbf2(float a, float b) {
  union { u32 u; __bf16 h[2]; } pk;
  pk.h[0] = (__bf16)a; pk.h[1] = (__bf16)b;
  return pk.u;
}
__device__ __forceinline__ float gelu_exact(float x) {
  return 0.5f * x * (1.f + erff(x * 0.7071067811865475f));
}
__device__ __forceinline__ void gload16(const void* g, void* l) {
  __builtin_amdgcn_global_load_lds((__attribute__((address_space(1))) void*)(g),
                                   (__attribute__((address_space(3))) void*)(l),
                                   16, 0, 0);
}

// ===========================================================================
// 128x128 GEMM, 4 waves (2x2), BK=64, dbuf 64KiB LDS — round-6 schedule.
// EPI: 0 = permuted bf16 -> [ts][B,H,S,DH], ts==0 plane scaled 0.125
//      1 = f32 out = res + acc + bias (in-place out==res elementwise-safe)
//      5 = permuted bf16, NO scale (KV fused store)
// ===========================================================================
template<int EPI>
__global__ __launch_bounds__(256, 2) void gemm128(
    const u16* __restrict__ A, const u16* __restrict__ BT,
    const float* __restrict__ bias, const float* __restrict__ res,
    void* __restrict__ out, int M, int N, int K, int ktiles)
{
  __shared__ u16 As[2][128 * 64];
  __shared__ u16 Bs[2][128 * 64];

  const int tid = threadIdx.x;
  const int wave = tid >> 6, lane = tid & 63;
  const int wm = wave >> 1, wn = wave & 1;
  const int qi = lane & 15, g = lane >> 4;

  const int gx = N >> 7;
  const int nwg = gx * (M >> 7);
  int id = blockIdx.y * gridDim.x + blockIdx.x;
  id = (id & 7) * (nwg >> 3) + (id >> 3);      // XCD swizzle (nwg % 8 == 0)
  const int m0 = (id / gx) << 7, n0 = (id % gx) << 7;

  const int NT = ktiles;
  const int kbase = blockIdx.z * ktiles * 64;

  const int r0 = tid >> 3;
  const int scol = (((tid & 7) ^ ((tid >> 3) & 7)) << 3);
  const int swb = wave << 6;

  f32x4 acc[4][4];
#pragma unroll
  for (int i = 0; i < 4; ++i)
#pragma unroll
    for (int j = 0; j < 4; ++j)
      acc[i][j] = (f32x4){0.f, 0.f, 0.f, 0.f};

#define STAGE_A(t, h, b) {                                                  \
    const int tt = (t) >= NT ? (t) - NT : (t);                              \
    _Pragma("unroll")                                                       \
    for (int i = 0; i < 2; ++i) {                                           \
      const int r = (h) * 64 + i * 32 + r0;                                 \
      gload16(A + (size_t)(m0 + r) * K + kbase + tt * 64 + scol,            \
              &As[b][(h) * 4096 + (i * 256 + swb) * 8]);                    \
    } }
#define STAGE_B(t, h, b) {                                                  \
    const int tt = (t) >= NT ? (t) - NT : (t);                              \
    _Pragma("unroll")                                                       \
    for (int i = 0; i < 2; ++i) {                                           \
      const int r = (h) * 64 + i * 32 + r0;                                 \
      gload16(BT + (size_t)(n0 + r) * K + kbase + tt * 64 + scol,           \
              &Bs[b][(h) * 4096 + (i * 256 + swb) * 8]);                    \
    } }

  bf16x8 af[4][2], bfr[4][2];

#define RD_ALL(b)                                                            \
  _Pragma("unroll") for (int mi = 0; mi < 4; ++mi)                           \
  _Pragma("unroll") for (int kk = 0; kk < 2; ++kk) {                         \
    const int row = wm * 64 + mi * 16 + qi;                                  \
    const int cb = ((kk * 64 + (g << 4)) ^ ((qi & 7) << 4));                 \
    af[mi][kk] = *(const bf16x8*)((const char*)&As[b][0] + row * 128 + cb);  \
  }                                                                          \
  _Pragma("unroll") for (int ni = 0; ni < 4; ++ni)                           \
  _Pragma("unroll") for (int kk = 0; kk < 2; ++kk) {                         \
    const int row = wn * 64 + ni * 16 + qi;                                  \
    const int cb = ((kk * 64 + (g << 4)) ^ ((qi & 7) << 4));                 \
    bfr[ni][kk] = *(const bf16x8*)((const char*)&Bs[b][0] + row * 128 + cb); \
  }

#define HALF(milo)                                                           \
  _Pragma("unroll") for (int mi = (milo); mi < (milo) + 2; ++mi)             \
  _Pragma("unroll") for (int ni = 0; ni < 4; ++ni)                           \
  _Pragma("unroll") for (int kk = 0; kk < 2; ++kk)                           \
    acc[mi][ni] = mfma16(af[mi][kk], bfr[ni][kk], acc[mi][ni]);

#define BAR() __builtin_amdgcn_s_barrier()
#define LGKM0() { asm volatile("s_waitcnt lgkmcnt(0)" ::: "memory");         \
                  __builtin_amdgcn_sched_barrier(0); }
#define VM8() asm volatile("s_waitcnt vmcnt(8)" ::: "memory")
#define PRIO(x) __builtin_amdgcn_s_setprio(x)

  STAGE_A(0, 0, 0); STAGE_A(0, 1, 0); STAGE_B(0, 0, 0); STAGE_B(0, 1, 0);
  STAGE_A(1, 0, 1); STAGE_A(1, 1, 1); STAGE_B(1, 0, 1); STAGE_B(1, 1, 1);
  VM8();
  BAR();

  const int NI = NT >> 1;
  for (int it = 0; it < NI; ++it) {
    const int k = it * 2;
    RD_ALL(0); LGKM0();
    BAR();
    STAGE_A(k + 2, 0, 0); STAGE_A(k + 2, 1, 0);
    PRIO(1); HALF(0); PRIO(0);
    STAGE_B(k + 2, 0, 0); STAGE_B(k + 2, 1, 0);
    PRIO(1); HALF(2); PRIO(0);
    VM8();
    BAR();
    RD_ALL(1); LGKM0();
    BAR();
    STAGE_A(k + 3, 0, 1); STAGE_A(k + 3, 1, 1);
    PRIO(1); HALF(0); PRIO(0);
    STAGE_B(k + 3, 0, 1); STAGE_B(k + 3, 1, 1);
    PRIO(1); HALF(2); PRIO(0);
    VM8();
    BAR();
  }

#pragma unroll
  for (int mi = 0; mi < 4; ++mi) {
#pragma unroll
    for (int ni = 0; ni < 4; ++ni) {
#pragma unroll
      for (int r = 0; r < 4; ++r) {
        const int m = m0 + wm * 64 + mi * 16 + g * 4 + r;
        const int n = n0 + wn * 64 + ni * 16 + qi;
        float v = acc[mi][ni][r];
        if (EPI == 0 || EPI == 5) {
          const int ts = n >> 10, b = m >> 10, s = m & 1023;
          const int hh = (n >> 6) & 15, dh = n & 63;
          if (EPI == 0 && ts == 0) v *= SCALE_;
          ((u16*)out)[(size_t)ts * (B_ * H_ * S_ * DH_) +
                      (((size_t)(b * H_ + hh) * S_) + s) * DH_ + dh] = f2bf(v);
        } else {
          const size_t idx = (size_t)m * N + n;
          ((float*)out)[idx] = res[idx] + v + bias[n];
        }
      }
    }
  }
#undef STAGE_A
#undef STAGE_B
#undef RD_ALL
#undef HALF
#undef BAR
#undef LGKM0
#undef VM8
#undef PRIO
}

// ===========================================================================
// Merged GEGLU FF1 — deep-pipeline version: A single-buffer (16KB), Bh/Bg
// double-buffered (2x32KB) = 80KB LDS -> 2 blocks/CU. Per tile:
//   RD_A + RD_Bh -> MFMA_h (compiler-interleaved) -> RD_Bg -> lgkmcnt(0) ->
//   BAR -> stage A(t+1)+Bh/Bg(t+2) -> MFMA_g -> vmcnt(8) -> BAR.
// Ledger: prologue B(0),A(0),B(1)=20 loads, vmcnt(8) drains B(0)+A(0);
// steady vmcnt(8) drains B(t+1)+A(t+1), leaves B(t+2) in flight.
// 2-D XCD map (FETCH 135.6 -> 49.4MB measured). launch_bounds(256,2) only
// (round-12: tighter cap spills the ~190-reg accumulator live set).
// ===========================================================================
__global__ __launch_bounds__(256, 2) void ffgeglu(
    const u16* __restrict__ A, const u16* __restrict__ BTh,
    const u16* __restrict__ BTg, const float* __restrict__ bias,
    u16* __restrict__ out)
{
  __shared__ u16 As[128 * 64];
  __shared__ u16 Bhs[2][128 * 64];
  __shared__ u16 Bgs[2][128 * 64];

  const int tid = threadIdx.x;
  const int wave = tid >> 6, lane = tid & 63;
  const int wm = wave >> 1, wn = wave & 1;
  const int qi = lane & 15, g = lane >> 4;

  // 2-D XCD ownership: XCD (cm,cn) in 2x4 owns a 16m x 8n tile rectangle.
  const int orig = blockIdx.y * gridDim.x + blockIdx.x;   // 1024 blocks
  const int c = orig & 7, j = orig >> 3;
  const int cm = c >> 2, cn = c & 3;
  const int jm = j & 15, jn = j >> 4;
  const int m0 = (cm * 16 + jm) << 7;
  const int n0 = (cn * 8 + jn) << 7;
  const int K = 1024;
  const int NT = 16;

  const int r0 = tid >> 3;
  const int scol = (((tid & 7) ^ ((tid >> 3) & 7)) << 3);
  const int swb = wave << 6;

  f32x4 acch[4][4], accg[4][4];
#pragma unroll
  for (int i = 0; i < 4; ++i)
#pragma unroll
    for (int j2 = 0; j2 < 4; ++j2) {
      acch[i][j2] = (f32x4){0.f, 0.f, 0.f, 0.f};
      accg[i][j2] = (f32x4){0.f, 0.f, 0.f, 0.f};
    }

#define FSTAGE_A(t) {                                                       \
    const int tt = (t) >= NT ? (t) - NT : (t);                              \
    _Pragma("unroll")                                                       \
    for (int i = 0; i < 4; ++i) {                                           \
      const int r = i * 32 + r0;                                            \
      gload16(A + (size_t)(m0 + r) * K + tt * 64 + scol,                    \
              &As[(i * 256 + swb) * 8]);                                    \
    } }
#define FSTAGE_BH(t, b) {                                                   \
    const int tt = (t) >= NT ? (t) - NT : (t);                              \
    _Pragma("unroll")                                                       \
    for (int i = 0; i < 4; ++i) {                                           \
      const int r = i * 32 + r0;                                            \
      gload16(BTh + (size_t)(n0 + r) * K + tt * 64 + scol,                  \
              &Bhs[b][(i * 256 + swb) * 8]);                                \
    } }
#define FSTAGE_BG(t, b) {                                                   \
    const int tt = (t) >= NT ? (t) - NT : (t);                              \
    _Pragma("unroll")                                                       \
    for (int i = 0; i < 4; ++i) {                                           \
      const int r = i * 32 + r0;                                            \
      gload16(BTg + (size_t)(n0 + r) * K + tt * 64 + scol,                  \
              &Bgs[b][(i * 256 + swb) * 8]);                                \
    } }

  bf16x8 af[4][2], bfr[4][2];

#define FRD_A()                                                              \
  _Pragma("unroll") for (int mi = 0; mi < 4; ++mi)                           \
  _Pragma("unroll") for (int kk = 0; kk < 2; ++kk) {                         \
    const int row = wm * 64 + mi * 16 + qi;                                  \
    const int cb = ((kk * 64 + (g << 4)) ^ ((qi & 7) << 4));                 \
    af[mi][kk] = *(const bf16x8*)((const char*)&As[0] + row * 128 + cb);     \
  }
#define FRD_B(base)                                                          \
  _Pragma("unroll") for (int ni = 0; ni < 4; ++ni)                           \
  _Pragma("unroll") for (int kk = 0; kk < 2; ++kk) {                         \
    const int row = wn * 64 + ni * 16 + qi;                                  \
    const int cb = ((kk * 64 + (g << 4)) ^ ((qi & 7) << 4));                 \
    bfr[ni][kk] = *(const bf16x8*)((const char*)(base) + row * 128 + cb);    \
  }
#define FMFMA(accx)                                                          \
  _Pragma("unroll") for (int mi = 0; mi < 4; ++mi)                           \
  _Pragma("unroll") for (int ni = 0; ni < 4; ++ni)                           \
  _Pragma("unroll") for (int kk = 0; kk < 2; ++kk)                           \
    accx[mi][ni] = mfma16(af[mi][kk], bfr[ni][kk], accx[mi][ni]);

#define BAR() __builtin_amdgcn_s_barrier()
#define LGKM0() { asm volatile("s_waitcnt lgkmcnt(0)" ::: "memory");         \
                  __builtin_amdgcn_sched_barrier(0); }
#define VM8() asm volatile("s_waitcnt vmcnt(8)" ::: "memory")
#define PRIO(x) __builtin_amdgcn_s_setprio(x)

  // prologue: B(0) -> buf0, A(0), B(1) -> buf1; vmcnt(8) drains B(0)+A(0)
  FSTAGE_BH(0, 0); FSTAGE_BG(0, 0);
  FSTAGE_A(0);
  FSTAGE_BH(1, 1); FSTAGE_BG(1, 1);
  VM8();
  BAR();

  for (int t = 0; t < NT; ++t) {
    const int b = t & 1;
    FRD_A();
    FRD_B(&Bhs[b][0]);
    PRIO(1); FMFMA(acch); PRIO(0);        // compiler interleaves reads+MFMA
    FRD_B(&Bgs[b][0]);
    LGKM0();                              // all LDS reads of this tile done
    BAR();                                // safe to overwrite As + buf b
    FSTAGE_A(t + 1);
    FSTAGE_BH(t + 2, b); FSTAGE_BG(t + 2, b);
    PRIO(1); FMFMA(accg); PRIO(0);
    VM8();                                // drains B(t+1)+A(t+1); B(t+2) flies
    BAR();
  }

#pragma unroll
  for (int mi = 0; mi < 4; ++mi) {
#pragma unroll
    for (int ni = 0; ni < 4; ++ni) {
#pragma unroll
      for (int r = 0; r < 4; ++r) {
        const int m = m0 + wm * 64 + mi * 16 + g * 4 + r;
        const int n = n0 + wn * 64 + ni * 16 + qi;
        const float hv = acch[mi][ni][r] + bias[n];
        const float gv = accg[mi][ni][r] + bias[FF_ + n];
        out[(size_t)m * FF_ + n] = f2bf(hv * gelu_exact(gv));
      }
    }
  }
#undef FSTAGE_A
#undef FSTAGE_BH
#undef FSTAGE_BG
#undef FRD_A
#undef FRD_B
#undef FMFMA
#undef BAR
#undef LGKM0
#undef VM8
#undef PRIO
}

// ---------------------------------------------------------------------------
// Flash attention. Q pre-scaled by 0.125. Fixed-max softmax (scores bounded;
// masked scores = -1e30 -> exp = 0). Direct LDS staging. 4 waves x 16 q-rows.
// ---------------------------------------------------------------------------
template<bool MASKED>
__global__ __launch_bounds__(256, 4) void attn_kernel(
    const u16* __restrict__ Q, const u16* __restrict__ Kb,
    const u16* __restrict__ VT, const float* __restrict__ bias,
    u16* __restrict__ O, int S, int T)
{
  __shared__ u16 Ks[64 * 72];
  __shared__ u16 VTs[64 * 72];
  __shared__ u16 Ps[4][16 * 72];
  __shared__ float biasS[64];

  const int bh = blockIdx.y;
  const int b = bh >> 4, h = bh & 15;
  const int tid = threadIdx.x;
  const int wave = tid >> 6, lane = tid & 63;
  const int g = lane >> 4, qi = lane & 15;
  const int q0w = blockIdx.x * 64 + wave * 16;

  const u16* Qb = Q + (size_t)bh * S * DH_;
  const u16* Kg = Kb + (size_t)bh * T * DH_;
  const u16* Vg = VT + (size_t)bh * DH_ * T;

  bf16x8 qf[2];
  qf[0] = *(const bf16x8*)&Qb[(q0w + qi) * DH_ + g * 8];
  qf[1] = *(const bf16x8*)&Qb[(q0w + qi) * DH_ + 32 + g * 8];

  f32x4 acc[4];
#pragma unroll
  for (int i = 0; i < 4; ++i) acc[i] = (f32x4){0.f, 0.f, 0.f, 0.f};
  float l_run = 1e-30f;

  u16* Pw = &Ps[wave][0];

  for (int t0 = 0; t0 < T; t0 += 64) {
    __syncthreads();
#pragma unroll
    for (int i = 0; i < 2; ++i) {
      const int flat = i * 256 + tid;
      const int row = flat >> 3, kc = flat & 7;
      *(uint4*)&Ks[row * 72 + kc * 8] = *(const uint4*)&Kg[(size_t)(t0 + row) * DH_ + kc * 8];
      *(uint4*)&VTs[row * 72 + kc * 8] = *(const uint4*)&Vg[(size_t)row * T + t0 + kc * 8];
    }
    if (MASKED && tid < 64) biasS[tid] = bias[b * T + t0 + tid];
    __syncthreads();

    f32x4 sacc[4];
#pragma unroll
    for (int nt = 0; nt < 4; ++nt) sacc[nt] = (f32x4){0.f, 0.f, 0.f, 0.f};
#pragma unroll
    for (int kk = 0; kk < 2; ++kk) {
#pragma unroll
      for (int nt = 0; nt < 4; ++nt) {
        bf16x8 kf = *(const bf16x8*)&Ks[(nt * 16 + qi) * 72 + kk * 32 + g * 8];
        sacc[nt] = mfma16(kf, qf[kk], sacc[nt]);
      }
    }
    float p[4][4];
    float lsum = 0.f;
#pragma unroll
    for (int nt = 0; nt < 4; ++nt)
#pragma unroll
      for (int r = 0; r < 4; ++r) {
        float v = sacc[nt][r];
        if (MASKED) v += biasS[nt * 16 + g * 4 + r];
        const float e = __expf(v);
        p[nt][r] = e;
        lsum += e;
      }
    lsum += __shfl_xor(lsum, 16);
    lsum += __shfl_xor(lsum, 32);
    l_run += lsum;

#pragma unroll
    for (int nt = 0; nt < 4; ++nt) {
      uint2 w;
      w.x = packbf2(p[nt][0], p[nt][1]);
      w.y = packbf2(p[nt][2], p[nt][3]);
      *(uint2*)&Pw[qi * 72 + nt * 16 + g * 4] = w;
    }

#pragma unroll
    for (int kk = 0; kk < 2; ++kk) {
      bf16x8 pf = *(const bf16x8*)&Pw[qi * 72 + kk * 32 + g * 8];
#pragma unroll
      for (int ndh = 0; ndh < 4; ++ndh) {
        bf16x8 vf = *(const bf16x8*)&VTs[(ndh * 16 + qi) * 72 + kk * 32 + g * 8];
        acc[ndh] = mfma16(vf, pf, acc[ndh]);
      }
    }
  }

  const float inv = 1.f / l_run;
  const int qg = q0w + qi;
#pragma unroll
  for (int ndh = 0; ndh < 4; ++ndh) {
    uint2 w;
    w.x = packbf2(acc[ndh][0] * inv, acc[ndh][1] * inv);
    w.y = packbf2(acc[ndh][2] * inv, acc[ndh][3] * inv);
    *(uint2*)&O[(size_t)(b * S_ + qg) * D_ + h * DH_ + ndh * 16 + g * 4] = w;
  }
}

// ---------------------------------------------------------------------------
__global__ __launch_bounds__(256) void ln_kernel(
    const float* __restrict__ x, const float* __restrict__ gg,
    const float* __restrict__ bb, u16* __restrict__ out)
{
  __shared__ float red[8];
  const int row = blockIdx.x, tid = threadIdx.x;
  const float4 v = ((const float4*)(x + (size_t)row * D_))[tid];
  float s = v.x + v.y + v.z + v.w;
  float sq = v.x * v.x + v.y * v.y + v.z * v.z + v.w * v.w;
#pragma unroll
  for (int m = 32; m; m >>= 1) {
    s += __shfl_xor(s, m);
    sq += __shfl_xor(sq, m);
  }
  const int wave = tid >> 6, lane = tid & 63;
  if (lane == 0) { red[wave * 2] = s; red[wave * 2 + 1] = sq; }
  __syncthreads();
  const float St = red[0] + red[2] + red[4] + red[6];
  const float SQt = red[1] + red[3] + red[5] + red[7];
  const float mean = St * (1.f / 1024.f);
  float var = SQt * (1.f / 1024.f) - mean * mean;
  var = fmaxf(var, 0.f);
  const float rinv = rsqrtf(var + 1e-12f);
  const float4 g4 = ((const float4*)gg)[tid];
  const float4 b4 = ((const float4*)bb)[tid];
  uint2 o;
  o.x = packbf2((v.x - mean) * rinv * g4.x + b4.x, (v.y - mean) * rinv * g4.y + b4.y);
  o.y = packbf2((v.z - mean) * rinv * g4.z + b4.z, (v.w - mean) * rinv * g4.w + b4.w);
  ((uint2*)(out + (size_t)row * D_))[tid] = o;
}

__global__ __launch_bounds__(256) void transpose_w(
    const float* __restrict__ in, u16* __restrict__ out, int K, int N)
{
  __shared__ float tile[32][33];
  const int tx = threadIdx.x & 31, ty = threadIdx.x >> 5;
  const int k0 = blockIdx.y * 32, n0 = blockIdx.x * 32;
#pragma unroll
  for (int j = 0; j < 4; ++j)
    tile[ty + 8 * j][tx] = in[(size_t)(k0 + ty + 8 * j) * N + n0 + tx];
  __syncthreads();
#pragma unroll
  for (int j = 0; j < 4; ++j)
    out[(size_t)(n0 + ty + 8 * j) * K + k0 + tx] = f2bf(tile[tx][ty + 8 * j]);
}

__global__ __launch_bounds__(256) void transpose_w8(
    const float* __restrict__ w0, const float* __restrict__ w1,
    const float* __restrict__ w2, const float* __restrict__ w3,
    const float* __restrict__ w4, const float* __restrict__ w5,
    const float* __restrict__ w6, const float* __restrict__ w7,
    u16* __restrict__ outbase)
{
  __shared__ float tile[32][33];
  const float* srcs[8] = {w0, w1, w2, w3, w4, w5, w6, w7};
  const float* in = srcs[blockIdx.z];
  u16* out = outbase + (size_t)blockIdx.z * 1024 * 1024;
  const int tx = threadIdx.x & 31, ty = threadIdx.x >> 5;
  const int k0 = blockIdx.y * 32, n0 = blockIdx.x * 32;
#pragma unroll
  for (int j = 0; j < 4; ++j)
    tile[ty + 8 * j][tx] = in[(size_t)(k0 + ty + 8 * j) * 1024 + n0 + tx];
  __syncthreads();
#pragma unroll
  for (int j = 0; j < 4; ++j)
    out[(size_t)(n0 + ty + 8 * j) * 1024 + k0 + tx] = f2bf(tile[tx][ty + 8 * j]);
}

__global__ __launch_bounds__(256) void transpose_v(
    const u16* __restrict__ in, u16* __restrict__ out, int T)
{
  __shared__ u16 tile[32][33];
  const int tx = threadIdx.x & 31, ty = threadIdx.x >> 5;
  const int bh = blockIdx.z;
  const int t0 = blockIdx.x * 32, d0 = blockIdx.y * 32;
  const u16* ib = in + (size_t)bh * T * DH_;
  u16* ob = out + (size_t)bh * DH_ * T;
#pragma unroll
  for (int j = 0; j < 4; ++j)
    tile[ty + 8 * j][tx] = ib[(size_t)(t0 + ty + 8 * j) * DH_ + d0 + tx];
  __syncthreads();
#pragma unroll
  for (int j = 0; j < 4; ++j)
    ob[(size_t)(d0 + ty + 8 * j) * T + t0 + tx] = tile[tx][ty + 8 * j];
}

__global__ void cvt_bf16(const float* __restrict__ in, u16* __restrict__ out, int n4)
{
  const int i = blockIdx.x * blockDim.x + threadIdx.x;
  if (i < n4) {
    const float4 v = ((const float4*)in)[i];
    uint2 o;
    o.x = packbf2(v.x, v.y);
    o.y = packbf2(v.z, v.w);
    ((uint2*)out)[i] = o;
  }
}

__global__ void mask_bias(const int* __restrict__ mask, float* __restrict__ bias, int n)
{
  const int i = blockIdx.x * blockDim.x + threadIdx.x;
  if (i < n) bias[i] = mask[i] ? 0.f : -1e30f;
}

// ---------------------------------------------------------------------------
extern "C" void kernel_launch(void* const* d_in, const int* in_sizes, int n_in,
                              void* d_out, int out_size, void* d_ws, size_t ws_size,
                              hipStream_t stream)
{
  (void)in_sizes; (void)n_in; (void)out_size; (void)ws_size;
  const float* hidden = (const float*)d_in[0];
  const float* ctx    = (const float*)d_in[1];
  const int*   mask   = (const int*)d_in[2];
  const float* g1 = (const float*)d_in[3];
  const float* b1 = (const float*)d_in[4];
  const float* g2 = (const float*)d_in[5];
  const float* b2 = (const float*)d_in[6];
  const float* g3 = (const float*)d_in[7];
  const float* b3 = (const float*)d_in[8];
  const float* Wq1 = (const float*)d_in[9];
  const float* Wk1 = (const float*)d_in[10];
  const float* Wv1 = (const float*)d_in[11];
  const float* Wo1 = (const float*)d_in[12];
  const float* bo1 = (const float*)d_in[13];
  const float* Wq2 = (const float*)d_in[14];
  const float* Wk2 = (const float*)d_in[15];
  const float* Wv2 = (const float*)d_in[16];
  const float* Wo2 = (const float*)d_in[17];
  const float* bo2 = (const float*)d_in[18];
  const float* Wff1 = (const float*)d_in[19];
  const float* bff1 = (const float*)d_in[20];
  const float* Wff2 = (const float*)d_in[21];
  const float* bff2 = (const float*)d_in[22];

  char* ws = (char*)d_ws;
  size_t off = 0;
  auto alloc = [&](size_t bytes) -> void* {
    void* p = ws + off;
    off += (bytes + 255) & ~(size_t)255;
    return p;
  };
  // WqT1..WoT2: 8 CONTIGUOUS 2MB blocks (transpose_w8 target).
  u16* WqT1  = (u16*)alloc((size_t)1024 * 1024 * 2);
  u16* WkT1  = (u16*)alloc((size_t)1024 * 1024 * 2);
  u16* WvT1  = (u16*)alloc((size_t)1024 * 1024 * 2);
  u16* WoT1  = (u16*)alloc((size_t)1024 * 1024 * 2);
  u16* WqT2  = (u16*)alloc((size_t)1024 * 1024 * 2);
  u16* WkT2  = (u16*)alloc((size_t)1024 * 1024 * 2);
  u16* WvT2  = (u16*)alloc((size_t)1024 * 1024 * 2);
  u16* WoT2  = (u16*)alloc((size_t)1024 * 1024 * 2);
  u16* Wff1T = (u16*)alloc((size_t)8192 * 1024 * 2);
  u16* Wff2T = (u16*)alloc((size_t)1024 * 4096 * 2);
  u16* nbuf  = (u16*)alloc((size_t)M_ * D_ * 2);
  u16* hgbuf = (u16*)alloc((size_t)M_ * FF_ * 2);
  u16* qbuf  = (u16*)alloc((size_t)M_ * D_ * 2);
  u16* kbuf  = (u16*)alloc((size_t)M_ * D_ * 2);
  u16* vbuf  = (u16*)alloc((size_t)M_ * D_ * 2);
  u16* vtbuf = (u16*)alloc((size_t)M_ * D_ * 2);
  u16* attnb = (u16*)alloc((size_t)M_ * D_ * 2);
  u16* ctxb  = (u16*)alloc((size_t)M_ * D_ * 2);
  float* biasw = (float*)alloc((size_t)B_ * S_ * 4);
  float* hres = (float*)d_out;   // residual chain lives in d_out (f32)
  (void)WkT1; (void)WvT1; (void)WkT2; (void)WvT2; (void)WoT2;

  const dim3 blk(256);
  const dim3 gW8(32, 32, 8);
  const dim3 gQKV(24, 32);       // N=3072 -> 768 blocks
  const dim3 gKV(16, 32);        // N=2048 -> 512 blocks
  const dim3 gP(8, 32);          // N=1024 -> 256 blocks (direct)
  const dim3 gFF(32, 32);        // merged GEGLU: 1024 blocks
  const dim3 gA(16, 64);
  const dim3 gV(32, 2, 64);

  // weight prep (batched)
  transpose_w8<<<gW8, blk, 0, stream>>>(Wq1, Wk1, Wv1, Wo1, Wq2, Wk2, Wv2, Wo2,
                                        WqT1);
  transpose_w<<<dim3(256, 32), blk, 0, stream>>>(Wff1, Wff1T, 1024, 8192);
  transpose_w<<<dim3(32, 128), blk, 0, stream>>>(Wff2, Wff2T, 4096, 1024);
  cvt_bf16<<<dim3(4096), blk, 0, stream>>>(ctx, ctxb, 1048576);
  mask_bias<<<dim3(16), blk, 0, stream>>>(mask, biasw, B_ * S_);

  // --- self attention ---
  ln_kernel<<<dim3(M_), blk, 0, stream>>>(hidden, g1, b1, nbuf);
  gemm128<0><<<gQKV, blk, 0, stream>>>(nbuf, WqT1, nullptr, nullptr,
                                       qbuf, M_, 3072, 1024, 16);
  transpose_v<<<gV, blk, 0, stream>>>(vbuf, vtbuf, 1024);
  attn_kernel<false><<<gA, blk, 0, stream>>>(qbuf, kbuf, vtbuf, nullptr, attnb,
                                             S_, S_);
  // h1 = hidden + attnO + bo1 (direct, f32 into d_out)
  gemm128<1><<<gP, blk, 0, stream>>>(attnb, WoT1, bo1, hidden,
                                     hres, M_, 1024, 1024, 16);
  ln_kernel<<<dim3(M_), blk, 0, stream>>>(hres, g2, b2, nbuf);

  // --- cross attention ---
  gemm128<0><<<gP, blk, 0, stream>>>(nbuf, WqT2, nullptr, nullptr,
                                     qbuf, M_, 1024, 1024, 16);   // Q2 (scaled)
  gemm128<5><<<gKV, blk, 0, stream>>>(ctxb, WkT2, nullptr, nullptr,
                                      kbuf, M_, 2048, 1024, 16);  // K2,V2 fused
  transpose_v<<<gV, blk, 0, stream>>>(vbuf, vtbuf, 1024);
  attn_kernel<true><<<gA, blk, 0, stream>>>(qbuf, kbuf, vtbuf, biasw, attnb,
                                            S_, S_);
  // h2 = h1 + attnO + bo2 (in-place on d_out; elementwise-safe)
  gemm128<1><<<gP, blk, 0, stream>>>(attnb, WoT2, bo2, hres,
                                     hres, M_, 1024, 1024, 16);
  ln_kernel<<<dim3(M_), blk, 0, stream>>>(hres, g3, b3, nbuf);

  // --- GEGLU FF ---
  ffgeglu<<<gFF, blk, 0, stream>>>(nbuf, Wff1T, Wff1T + (size_t)FF_ * 1024,
                                   bff1, hgbuf);
  // out = h2 + (hg @ Wff2) + bff2 (direct, in-place on d_out)
  gemm128<1><<<gP, blk, 0, stream>>>(hgbuf, Wff2T, bff2, hres,
                                     hres, M_, 1024, 4096, 64);
}

// Round 16
// 355.110 us; speedup vs baseline: 1.0461x; 1.0461x over previous
//
#include <hip/hip_runtime.h>

typedef unsigned short u16;
typedef unsigned int u32;

#define B_ 4
#define S_ 1024
#define D_ 1024
#define H_ 16
#define DH_ 64
#define FF_ 4096
#define M_ 4096
#define SCALE_ 0.125f

typedef __attribute__((ext_vector_type(8))) __bf16 bf16x8;
typedef __attribute__((ext_vector_type(4))) float f32x4;

__device__ __forceinline__ f32x4 mfma16(bf16x8 a, bf16x8 b, f32x4 c) {
  return __builtin_amdgcn_mfma_f32_16x16x32_bf16(a, b, c, 0, 0, 0);
}

// native converts -> compiler emits v_cvt_pk_bf16_f32 (catalog m240)
__device__ __forceinline__ u16 f2bf(float x) {
  union { __bf16 h; u16 u; } cv; cv.h = (__bf16)x; return cv.u;
}
__device__ __forceinline__ float bf2f(u16 u) {
  union { u32 u; float f; } cv; cv.u = ((u32)u) << 16; return cv.f;
}
__device__ __forceinline__ u32 packbf2(float a, float b) {
  union { u32 u; __bf16 h[2]; } pk;
  pk.h[0] = (__bf16)a; pk.h[1] = (__bf16)b;
  return pk.u;
}
__device__ __forceinline__ float gelu_exact(float x) {
  return 0.5f * x * (1.f + erff(x * 0.7071067811865475f));
}
__device__ __forceinline__ void gload16(const void* g, void* l) {
  __builtin_amdgcn_global_load_lds((__attribute__((address_space(1))) void*)(g),
                                   (__attribute__((address_space(3))) void*)(l),
                                   16, 0, 0);
}

// ===========================================================================
// 128x128 GEMM, 4 waves (2x2), BK=64, dbuf 64KiB LDS — round-6 schedule.
// EPI: 0 = permuted bf16 -> [ts][B,H,S,DH], ts==0 plane scaled 0.125
//      1 = f32 out = res + acc + bias (in-place out==res elementwise-safe)
//      5 = permuted bf16, NO scale (KV fused store)
// ===========================================================================
template<int EPI>
__global__ __launch_bounds__(256, 2) void gemm128(
    const u16* __restrict__ A, const u16* __restrict__ BT,
    const float* __restrict__ bias, const float* __restrict__ res,
    void* __restrict__ out, int M, int N, int K, int ktiles)
{
  __shared__ u16 As[2][128 * 64];
  __shared__ u16 Bs[2][128 * 64];

  const int tid = threadIdx.x;
  const int wave = tid >> 6, lane = tid & 63;
  const int wm = wave >> 1, wn = wave & 1;
  const int qi = lane & 15, g = lane >> 4;

  const int gx = N >> 7;
  const int nwg = gx * (M >> 7);
  int id = blockIdx.y * gridDim.x + blockIdx.x;
  id = (id & 7) * (nwg >> 3) + (id >> 3);      // XCD swizzle (nwg % 8 == 0)
  const int m0 = (id / gx) << 7, n0 = (id % gx) << 7;

  const int NT = ktiles;
  const int kbase = blockIdx.z * ktiles * 64;

  const int r0 = tid >> 3;
  const int scol = (((tid & 7) ^ ((tid >> 3) & 7)) << 3);
  const int swb = wave << 6;

  f32x4 acc[4][4];
#pragma unroll
  for (int i = 0; i < 4; ++i)
#pragma unroll
    for (int j = 0; j < 4; ++j)
      acc[i][j] = (f32x4){0.f, 0.f, 0.f, 0.f};

#define STAGE_A(t, h, b) {                                                  \
    const int tt = (t) >= NT ? (t) - NT : (t);                              \
    _Pragma("unroll")                                                       \
    for (int i = 0; i < 2; ++i) {                                           \
      const int r = (h) * 64 + i * 32 + r0;                                 \
      gload16(A + (size_t)(m0 + r) * K + kbase + tt * 64 + scol,            \
              &As[b][(h) * 4096 + (i * 256 + swb) * 8]);                    \
    } }
#define STAGE_B(t, h, b) {                                                  \
    const int tt = (t) >= NT ? (t) - NT : (t);                              \
    _Pragma("unroll")                                                       \
    for (int i = 0; i < 2; ++i) {                                           \
      const int r = (h) * 64 + i * 32 + r0;                                 \
      gload16(BT + (size_t)(n0 + r) * K + kbase + tt * 64 + scol,           \
              &Bs[b][(h) * 4096 + (i * 256 + swb) * 8]);                    \
    } }

  bf16x8 af[4][2], bfr[4][2];

#define RD_ALL(b)                                                            \
  _Pragma("unroll") for (int mi = 0; mi < 4; ++mi)                           \
  _Pragma("unroll") for (int kk = 0; kk < 2; ++kk) {                         \
    const int row = wm * 64 + mi * 16 + qi;                                  \
    const int cb = ((kk * 64 + (g << 4)) ^ ((qi & 7) << 4));                 \
    af[mi][kk] = *(const bf16x8*)((const char*)&As[b][0] + row * 128 + cb);  \
  }                                                                          \
  _Pragma("unroll") for (int ni = 0; ni < 4; ++ni)                           \
  _Pragma("unroll") for (int kk = 0; kk < 2; ++kk) {                         \
    const int row = wn * 64 + ni * 16 + qi;                                  \
    const int cb = ((kk * 64 + (g << 4)) ^ ((qi & 7) << 4));                 \
    bfr[ni][kk] = *(const bf16x8*)((const char*)&Bs[b][0] + row * 128 + cb); \
  }

#define HALF(milo)                                                           \
  _Pragma("unroll") for (int mi = (milo); mi < (milo) + 2; ++mi)             \
  _Pragma("unroll") for (int ni = 0; ni < 4; ++ni)                           \
  _Pragma("unroll") for (int kk = 0; kk < 2; ++kk)                           \
    acc[mi][ni] = mfma16(af[mi][kk], bfr[ni][kk], acc[mi][ni]);

#define BAR() __builtin_amdgcn_s_barrier()
#define LGKM0() { asm volatile("s_waitcnt lgkmcnt(0)" ::: "memory");         \
                  __builtin_amdgcn_sched_barrier(0); }
#define VM8() asm volatile("s_waitcnt vmcnt(8)" ::: "memory")
#define PRIO(x) __builtin_amdgcn_s_setprio(x)

  STAGE_A(0, 0, 0); STAGE_A(0, 1, 0); STAGE_B(0, 0, 0); STAGE_B(0, 1, 0);
  STAGE_A(1, 0, 1); STAGE_A(1, 1, 1); STAGE_B(1, 0, 1); STAGE_B(1, 1, 1);
  VM8();
  BAR();

  const int NI = NT >> 1;
  for (int it = 0; it < NI; ++it) {
    const int k = it * 2;
    RD_ALL(0); LGKM0();
    BAR();
    STAGE_A(k + 2, 0, 0); STAGE_A(k + 2, 1, 0);
    PRIO(1); HALF(0); PRIO(0);
    STAGE_B(k + 2, 0, 0); STAGE_B(k + 2, 1, 0);
    PRIO(1); HALF(2); PRIO(0);
    VM8();
    BAR();
    RD_ALL(1); LGKM0();
    BAR();
    STAGE_A(k + 3, 0, 1); STAGE_A(k + 3, 1, 1);
    PRIO(1); HALF(0); PRIO(0);
    STAGE_B(k + 3, 0, 1); STAGE_B(k + 3, 1, 1);
    PRIO(1); HALF(2); PRIO(0);
    VM8();
    BAR();
  }

#pragma unroll
  for (int mi = 0; mi < 4; ++mi) {
#pragma unroll
    for (int ni = 0; ni < 4; ++ni) {
#pragma unroll
      for (int r = 0; r < 4; ++r) {
        const int m = m0 + wm * 64 + mi * 16 + g * 4 + r;
        const int n = n0 + wn * 64 + ni * 16 + qi;
        float v = acc[mi][ni][r];
        if (EPI == 0 || EPI == 5) {
          const int ts = n >> 10, b = m >> 10, s = m & 1023;
          const int hh = (n >> 6) & 15, dh = n & 63;
          if (EPI == 0 && ts == 0) v *= SCALE_;
          ((u16*)out)[(size_t)ts * (B_ * H_ * S_ * DH_) +
                      (((size_t)(b * H_ + hh) * S_) + s) * DH_ + dh] = f2bf(v);
        } else {
          const size_t idx = (size_t)m * N + n;
          ((float*)out)[idx] = res[idx] + v + bias[n];
        }
      }
    }
  }
#undef STAGE_A
#undef STAGE_B
#undef RD_ALL
#undef HALF
#undef BAR
#undef LGKM0
#undef VM8
#undef PRIO
}

// ===========================================================================
// Merged GEGLU FF1 — round-14 proven version (best measured: 78 µs):
// single-buffer 48 KiB LDS, 2-D XCD ownership map (FETCH 135.6 -> 49.4 MB
// measured), __launch_bounds__(256,2).
// NOTE: do NOT raise the min-waves bound (round-12: spill, 4x slower) and do
// NOT deep-pipeline the B buffers (round-15: VGPR 128 / WRITE 52MB / +16%).
// ===========================================================================
__global__ __launch_bounds__(256, 2) void ffgeglu(
    const u16* __restrict__ A, const u16* __restrict__ BTh,
    const u16* __restrict__ BTg, const float* __restrict__ bias,
    u16* __restrict__ out)
{
  __shared__ u16 As[128 * 64];
  __shared__ u16 Bhs[128 * 64];
  __shared__ u16 Bgs[128 * 64];

  const int tid = threadIdx.x;
  const int wave = tid >> 6, lane = tid & 63;
  const int wm = wave >> 1, wn = wave & 1;
  const int qi = lane & 15, g = lane >> 4;

  // 2-D XCD ownership: XCD (cm,cn) in 2x4 owns a 16m x 8n tile rectangle.
  const int orig = blockIdx.y * gridDim.x + blockIdx.x;   // 1024 blocks
  const int c = orig & 7, j = orig >> 3;
  const int cm = c >> 2, cn = c & 3;
  const int jm = j & 15, jn = j >> 4;
  const int m0 = (cm * 16 + jm) << 7;
  const int n0 = (cn * 8 + jn) << 7;
  const int K = 1024;

  const int r0 = tid >> 3;
  const int scol = (((tid & 7) ^ ((tid >> 3) & 7)) << 3);
  const int swb = wave << 6;

  f32x4 acch[4][4], accg[4][4];
#pragma unroll
  for (int i = 0; i < 4; ++i)
#pragma unroll
    for (int j2 = 0; j2 < 4; ++j2) {
      acch[i][j2] = (f32x4){0.f, 0.f, 0.f, 0.f};
      accg[i][j2] = (f32x4){0.f, 0.f, 0.f, 0.f};
    }

  for (int t = 0; t < 16; ++t) {
    if (t) __syncthreads();
#pragma unroll
    for (int i = 0; i < 4; ++i) {
      const int r = i * 32 + r0;
      gload16(A + (size_t)(m0 + r) * K + t * 64 + scol,
              &As[(i * 256 + swb) * 8]);
    }
#pragma unroll
    for (int i = 0; i < 4; ++i) {
      const int r = i * 32 + r0;
      gload16(BTh + (size_t)(n0 + r) * K + t * 64 + scol,
              &Bhs[(i * 256 + swb) * 8]);
    }
#pragma unroll
    for (int i = 0; i < 4; ++i) {
      const int r = i * 32 + r0;
      gload16(BTg + (size_t)(n0 + r) * K + t * 64 + scol,
              &Bgs[(i * 256 + swb) * 8]);
    }
    __syncthreads();

    bf16x8 af[4][2], bfr[4][2];
#pragma unroll
    for (int mi = 0; mi < 4; ++mi)
#pragma unroll
      for (int kk = 0; kk < 2; ++kk) {
        const int row = wm * 64 + mi * 16 + qi;
        const int cb = ((kk * 64 + (g << 4)) ^ ((qi & 7) << 4));
        af[mi][kk] = *(const bf16x8*)((const char*)&As[0] + row * 128 + cb);
      }
    // ---- h half ----
#pragma unroll
    for (int ni = 0; ni < 4; ++ni)
#pragma unroll
      for (int kk = 0; kk < 2; ++kk) {
        const int row = wn * 64 + ni * 16 + qi;
        const int cb = ((kk * 64 + (g << 4)) ^ ((qi & 7) << 4));
        bfr[ni][kk] = *(const bf16x8*)((const char*)&Bhs[0] + row * 128 + cb);
      }
#pragma unroll
    for (int mi = 0; mi < 4; ++mi)
#pragma unroll
      for (int ni = 0; ni < 4; ++ni)
#pragma unroll
        for (int kk = 0; kk < 2; ++kk)
          acch[mi][ni] = mfma16(af[mi][kk], bfr[ni][kk], acch[mi][ni]);
    // ---- gate half (bfr reused) ----
#pragma unroll
    for (int ni = 0; ni < 4; ++ni)
#pragma unroll
      for (int kk = 0; kk < 2; ++kk) {
        const int row = wn * 64 + ni * 16 + qi;
        const int cb = ((kk * 64 + (g << 4)) ^ ((qi & 7) << 4));
        bfr[ni][kk] = *(const bf16x8*)((const char*)&Bgs[0] + row * 128 + cb);
      }
#pragma unroll
    for (int mi = 0; mi < 4; ++mi)
#pragma unroll
      for (int ni = 0; ni < 4; ++ni)
#pragma unroll
        for (int kk = 0; kk < 2; ++kk)
          accg[mi][ni] = mfma16(af[mi][kk], bfr[ni][kk], accg[mi][ni]);
  }

#pragma unroll
  for (int mi = 0; mi < 4; ++mi) {
#pragma unroll
    for (int ni = 0; ni < 4; ++ni) {
#pragma unroll
      for (int r = 0; r < 4; ++r) {
        const int m = m0 + wm * 64 + mi * 16 + g * 4 + r;
        const int n = n0 + wn * 64 + ni * 16 + qi;
        const float hv = acch[mi][ni][r] + bias[n];
        const float gv = accg[mi][ni][r] + bias[FF_ + n];
        out[(size_t)m * FF_ + n] = f2bf(hv * gelu_exact(gv));
      }
    }
  }
}

// ---------------------------------------------------------------------------
// Flash attention. Q pre-scaled by 0.125. Fixed-max softmax (scores bounded;
// masked scores = -1e30 -> exp = 0). Direct LDS staging. 4 waves x 16 q-rows.
// ---------------------------------------------------------------------------
template<bool MASKED>
__global__ __launch_bounds__(256, 4) void attn_kernel(
    const u16* __restrict__ Q, const u16* __restrict__ Kb,
    const u16* __restrict__ VT, const float* __restrict__ bias,
    u16* __restrict__ O, int S, int T)
{
  __shared__ u16 Ks[64 * 72];
  __shared__ u16 VTs[64 * 72];
  __shared__ u16 Ps[4][16 * 72];
  __shared__ float biasS[64];

  const int bh = blockIdx.y;
  const int b = bh >> 4, h = bh & 15;
  const int tid = threadIdx.x;
  const int wave = tid >> 6, lane = tid & 63;
  const int g = lane >> 4, qi = lane & 15;
  const int q0w = blockIdx.x * 64 + wave * 16;

  const u16* Qb = Q + (size_t)bh * S * DH_;
  const u16* Kg = Kb + (size_t)bh * T * DH_;
  const u16* Vg = VT + (size_t)bh * DH_ * T;

  bf16x8 qf[2];
  qf[0] = *(const bf16x8*)&Qb[(q0w + qi) * DH_ + g * 8];
  qf[1] = *(const bf16x8*)&Qb[(q0w + qi) * DH_ + 32 + g * 8];

  f32x4 acc[4];
#pragma unroll
  for (int i = 0; i < 4; ++i) acc[i] = (f32x4){0.f, 0.f, 0.f, 0.f};
  float l_run = 1e-30f;

  u16* Pw = &Ps[wave][0];

  for (int t0 = 0; t0 < T; t0 += 64) {
    __syncthreads();
#pragma unroll
    for (int i = 0; i < 2; ++i) {
      const int flat = i * 256 + tid;
      const int row = flat >> 3, kc = flat & 7;
      *(uint4*)&Ks[row * 72 + kc * 8] = *(const uint4*)&Kg[(size_t)(t0 + row) * DH_ + kc * 8];
      *(uint4*)&VTs[row * 72 + kc * 8] = *(const uint4*)&Vg[(size_t)row * T + t0 + kc * 8];
    }
    if (MASKED && tid < 64) biasS[tid] = bias[b * T + t0 + tid];
    __syncthreads();

    f32x4 sacc[4];
#pragma unroll
    for (int nt = 0; nt < 4; ++nt) sacc[nt] = (f32x4){0.f, 0.f, 0.f, 0.f};
#pragma unroll
    for (int kk = 0; kk < 2; ++kk) {
#pragma unroll
      for (int nt = 0; nt < 4; ++nt) {
        bf16x8 kf = *(const bf16x8*)&Ks[(nt * 16 + qi) * 72 + kk * 32 + g * 8];
        sacc[nt] = mfma16(kf, qf[kk], sacc[nt]);
      }
    }
    float p[4][4];
    float lsum = 0.f;
#pragma unroll
    for (int nt = 0; nt < 4; ++nt)
#pragma unroll
      for (int r = 0; r < 4; ++r) {
        float v = sacc[nt][r];
        if (MASKED) v += biasS[nt * 16 + g * 4 + r];
        const float e = __expf(v);
        p[nt][r] = e;
        lsum += e;
      }
    lsum += __shfl_xor(lsum, 16);
    lsum += __shfl_xor(lsum, 32);
    l_run += lsum;

#pragma unroll
    for (int nt = 0; nt < 4; ++nt) {
      uint2 w;
      w.x = packbf2(p[nt][0], p[nt][1]);
      w.y = packbf2(p[nt][2], p[nt][3]);
      *(uint2*)&Pw[qi * 72 + nt * 16 + g * 4] = w;
    }

#pragma unroll
    for (int kk = 0; kk < 2; ++kk) {
      bf16x8 pf = *(const bf16x8*)&Pw[qi * 72 + kk * 32 + g * 8];
#pragma unroll
      for (int ndh = 0; ndh < 4; ++ndh) {
        bf16x8 vf = *(const bf16x8*)&VTs[(ndh * 16 + qi) * 72 + kk * 32 + g * 8];
        acc[ndh] = mfma16(vf, pf, acc[ndh]);
      }
    }
  }

  const float inv = 1.f / l_run;
  const int qg = q0w + qi;
#pragma unroll
  for (int ndh = 0; ndh < 4; ++ndh) {
    uint2 w;
    w.x = packbf2(acc[ndh][0] * inv, acc[ndh][1] * inv);
    w.y = packbf2(acc[ndh][2] * inv, acc[ndh][3] * inv);
    *(uint2*)&O[(size_t)(b * S_ + qg) * D_ + h * DH_ + ndh * 16 + g * 4] = w;
  }
}

// ---------------------------------------------------------------------------
__global__ __launch_bounds__(256) void ln_kernel(
    const float* __restrict__ x, const float* __restrict__ gg,
    const float* __restrict__ bb, u16* __restrict__ out)
{
  __shared__ float red[8];
  const int row = blockIdx.x, tid = threadIdx.x;
  const float4 v = ((const float4*)(x + (size_t)row * D_))[tid];
  float s = v.x + v.y + v.z + v.w;
  float sq = v.x * v.x + v.y * v.y + v.z * v.z + v.w * v.w;
#pragma unroll
  for (int m = 32; m; m >>= 1) {
    s += __shfl_xor(s, m);
    sq += __shfl_xor(sq, m);
  }
  const int wave = tid >> 6, lane = tid & 63;
  if (lane == 0) { red[wave * 2] = s; red[wave * 2 + 1] = sq; }
  __syncthreads();
  const float St = red[0] + red[2] + red[4] + red[6];
  const float SQt = red[1] + red[3] + red[5] + red[7];
  const float mean = St * (1.f / 1024.f);
  float var = SQt * (1.f / 1024.f) - mean * mean;
  var = fmaxf(var, 0.f);
  const float rinv = rsqrtf(var + 1e-12f);
  const float4 g4 = ((const float4*)gg)[tid];
  const float4 b4 = ((const float4*)bb)[tid];
  uint2 o;
  o.x = packbf2((v.x - mean) * rinv * g4.x + b4.x, (v.y - mean) * rinv * g4.y + b4.y);
  o.y = packbf2((v.z - mean) * rinv * g4.z + b4.z, (v.w - mean) * rinv * g4.w + b4.w);
  ((uint2*)(out + (size_t)row * D_))[tid] = o;
}

__global__ __launch_bounds__(256) void transpose_w(
    const float* __restrict__ in, u16* __restrict__ out, int K, int N)
{
  __shared__ float tile[32][33];
  const int tx = threadIdx.x & 31, ty = threadIdx.x >> 5;
  const int k0 = blockIdx.y * 32, n0 = blockIdx.x * 32;
#pragma unroll
  for (int j = 0; j < 4; ++j)
    tile[ty + 8 * j][tx] = in[(size_t)(k0 + ty + 8 * j) * N + n0 + tx];
  __syncthreads();
#pragma unroll
  for (int j = 0; j < 4; ++j)
    out[(size_t)(n0 + ty + 8 * j) * K + k0 + tx] = f2bf(tile[tx][ty + 8 * j]);
}

__global__ __launch_bounds__(256) void transpose_w8(
    const float* __restrict__ w0, const float* __restrict__ w1,
    const float* __restrict__ w2, const float* __restrict__ w3,
    const float* __restrict__ w4, const float* __restrict__ w5,
    const float* __restrict__ w6, const float* __restrict__ w7,
    u16* __restrict__ outbase)
{
  __shared__ float tile[32][33];
  const float* srcs[8] = {w0, w1, w2, w3, w4, w5, w6, w7};
  const float* in = srcs[blockIdx.z];
  u16* out = outbase + (size_t)blockIdx.z * 1024 * 1024;
  const int tx = threadIdx.x & 31, ty = threadIdx.x >> 5;
  const int k0 = blockIdx.y * 32, n0 = blockIdx.x * 32;
#pragma unroll
  for (int j = 0; j < 4; ++j)
    tile[ty + 8 * j][tx] = in[(size_t)(k0 + ty + 8 * j) * 1024 + n0 + tx];
  __syncthreads();
#pragma unroll
  for (int j = 0; j < 4; ++j)
    out[(size_t)(n0 + ty + 8 * j) * 1024 + k0 + tx] = f2bf(tile[tx][ty + 8 * j]);
}

__global__ __launch_bounds__(256) void transpose_v(
    const u16* __restrict__ in, u16* __restrict__ out, int T)
{
  __shared__ u16 tile[32][33];
  const int tx = threadIdx.x & 31, ty = threadIdx.x >> 5;
  const int bh = blockIdx.z;
  const int t0 = blockIdx.x * 32, d0 = blockIdx.y * 32;
  const u16* ib = in + (size_t)bh * T * DH_;
  u16* ob = out + (size_t)bh * DH_ * T;
#pragma unroll
  for (int j = 0; j < 4; ++j)
    tile[ty + 8 * j][tx] = ib[(size_t)(t0 + ty + 8 * j) * DH_ + d0 + tx];
  __syncthreads();
#pragma unroll
  for (int j = 0; j < 4; ++j)
    ob[(size_t)(d0 + ty + 8 * j) * T + t0 + tx] = tile[tx][ty + 8 * j];
}

__global__ void cvt_bf16(const float* __restrict__ in, u16* __restrict__ out, int n4)
{
  const int i = blockIdx.x * blockDim.x + threadIdx.x;
  if (i < n4) {
    const float4 v = ((const float4*)in)[i];
    uint2 o;
    o.x = packbf2(v.x, v.y);
    o.y = packbf2(v.z, v.w);
    ((uint2*)out)[i] = o;
  }
}

__global__ void mask_bias(const int* __restrict__ mask, float* __restrict__ bias, int n)
{
  const int i = blockIdx.x * blockDim.x + threadIdx.x;
  if (i < n) bias[i] = mask[i] ? 0.f : -1e30f;
}

// ---------------------------------------------------------------------------
extern "C" void kernel_launch(void* const* d_in, const int* in_sizes, int n_in,
                              void* d_out, int out_size, void* d_ws, size_t ws_size,
                              hipStream_t stream)
{
  (void)in_sizes; (void)n_in; (void)out_size; (void)ws_size;
  const float* hidden = (const float*)d_in[0];
  const float* ctx    = (const float*)d_in[1];
  const int*   mask   = (const int*)d_in[2];
  const float* g1 = (const float*)d_in[3];
  const float* b1 = (const float*)d_in[4];
  const float* g2 = (const float*)d_in[5];
  const float* b2 = (const float*)d_in[6];
  const float* g3 = (const float*)d_in[7];
  const float* b3 = (const float*)d_in[8];
  const float* Wq1 = (const float*)d_in[9];
  const float* Wk1 = (const float*)d_in[10];
  const float* Wv1 = (const float*)d_in[11];
  const float* Wo1 = (const float*)d_in[12];
  const float* bo1 = (const float*)d_in[13];
  const float* Wq2 = (const float*)d_in[14];
  const float* Wk2 = (const float*)d_in[15];
  const float* Wv2 = (const float*)d_in[16];
  const float* Wo2 = (const float*)d_in[17];
  const float* bo2 = (const float*)d_in[18];
  const float* Wff1 = (const float*)d_in[19];
  const float* bff1 = (const float*)d_in[20];
  const float* Wff2 = (const float*)d_in[21];
  const float* bff2 = (const float*)d_in[22];

  char* ws = (char*)d_ws;
  size_t off = 0;
  auto alloc = [&](size_t bytes) -> void* {
    void* p = ws + off;
    off += (bytes + 255) & ~(size_t)255;
    return p;
  };
  // WqT1..WoT2: 8 CONTIGUOUS 2MB blocks (transpose_w8 target).
  u16* WqT1  = (u16*)alloc((size_t)1024 * 1024 * 2);
  u16* WkT1  = (u16*)alloc((size_t)1024 * 1024 * 2);
  u16* WvT1  = (u16*)alloc((size_t)1024 * 1024 * 2);
  u16* WoT1  = (u16*)alloc((size_t)1024 * 1024 * 2);
  u16* WqT2  = (u16*)alloc((size_t)1024 * 1024 * 2);
  u16* WkT2  = (u16*)alloc((size_t)1024 * 1024 * 2);
  u16* WvT2  = (u16*)alloc((size_t)1024 * 1024 * 2);
  u16* WoT2  = (u16*)alloc((size_t)1024 * 1024 * 2);
  u16* Wff1T = (u16*)alloc((size_t)8192 * 1024 * 2);
  u16* Wff2T = (u16*)alloc((size_t)1024 * 4096 * 2);
  u16* nbuf  = (u16*)alloc((size_t)M_ * D_ * 2);
  u16* hgbuf = (u16*)alloc((size_t)M_ * FF_ * 2);
  u16* qbuf  = (u16*)alloc((size_t)M_ * D_ * 2);
  u16* kbuf  = (u16*)alloc((size_t)M_ * D_ * 2);
  u16* vbuf  = (u16*)alloc((size_t)M_ * D_ * 2);
  u16* vtbuf = (u16*)alloc((size_t)M_ * D_ * 2);
  u16* attnb = (u16*)alloc((size_t)M_ * D_ * 2);
  u16* ctxb  = (u16*)alloc((size_t)M_ * D_ * 2);
  float* biasw = (float*)alloc((size_t)B_ * S_ * 4);
  float* hres = (float*)d_out;   // residual chain lives in d_out (f32)
  (void)WkT1; (void)WvT1; (void)WkT2; (void)WvT2; (void)WoT2;

  const dim3 blk(256);
  const dim3 gW8(32, 32, 8);
  const dim3 gQKV(24, 32);       // N=3072 -> 768 blocks
  const dim3 gKV(16, 32);        // N=2048 -> 512 blocks
  const dim3 gP(8, 32);          // N=1024 -> 256 blocks (direct)
  const dim3 gFF(32, 32);        // merged GEGLU: 1024 blocks
  const dim3 gA(16, 64);
  const dim3 gV(32, 2, 64);

  // weight prep (batched)
  transpose_w8<<<gW8, blk, 0, stream>>>(Wq1, Wk1, Wv1, Wo1, Wq2, Wk2, Wv2, Wo2,
                                        WqT1);
  transpose_w<<<dim3(256, 32), blk, 0, stream>>>(Wff1, Wff1T, 1024, 8192);
  transpose_w<<<dim3(32, 128), blk, 0, stream>>>(Wff2, Wff2T, 4096, 1024);
  cvt_bf16<<<dim3(4096), blk, 0, stream>>>(ctx, ctxb, 1048576);
  mask_bias<<<dim3(16), blk, 0, stream>>>(mask, biasw, B_ * S_);

  // --- self attention ---
  ln_kernel<<<dim3(M_), blk, 0, stream>>>(hidden, g1, b1, nbuf);
  gemm128<0><<<gQKV, blk, 0, stream>>>(nbuf, WqT1, nullptr, nullptr,
                                       qbuf, M_, 3072, 1024, 16);
  transpose_v<<<gV, blk, 0, stream>>>(vbuf, vtbuf, 1024);
  attn_kernel<false><<<gA, blk, 0, stream>>>(qbuf, kbuf, vtbuf, nullptr, attnb,
                                             S_, S_);
  // h1 = hidden + attnO + bo1 (direct, f32 into d_out)
  gemm128<1><<<gP, blk, 0, stream>>>(attnb, WoT1, bo1, hidden,
                                     hres, M_, 1024, 1024, 16);
  ln_kernel<<<dim3(M_), blk, 0, stream>>>(hres, g2, b2, nbuf);

  // --- cross attention ---
  gemm128<0><<<gP, blk, 0, stream>>>(nbuf, WqT2, nullptr, nullptr,
                                     qbuf, M_, 1024, 1024, 16);   // Q2 (scaled)
  gemm128<5><<<gKV, blk, 0, stream>>>(ctxb, WkT2, nullptr, nullptr,
                                      kbuf, M_, 2048, 1024, 16);  // K2,V2 fused
  transpose_v<<<gV, blk, 0, stream>>>(vbuf, vtbuf, 1024);
  attn_kernel<true><<<gA, blk, 0, stream>>>(qbuf, kbuf, vtbuf, biasw, attnb,
                                            S_, S_);
  // h2 = h1 + attnO + bo2 (in-place on d_out; elementwise-safe)
  gemm128<1><<<gP, blk, 0, stream>>>(attnb, WoT2, bo2, hres,
                                     hres, M_, 1024, 1024, 16);
  ln_kernel<<<dim3(M_), blk, 0, stream>>>(hres, g3, b3, nbuf);

  // --- GEGLU FF ---
  ffgeglu<<<gFF, blk, 0, stream>>>(nbuf, Wff1T, Wff1T + (size_t)FF_ * 1024,
                                   bff1, hgbuf);
  // out = h2 + (hg @ Wff2) + bff2 (direct, in-place on d_out)
  gemm128<1><<<gP, blk, 0, stream>>>(hgbuf, Wff2T, bff2, hres,
                                     hres, M_, 1024, 4096, 64);
}

// Round 17
// 343.693 us; speedup vs baseline: 1.0809x; 1.0332x over previous
//
#include <hip/hip_runtime.h>

typedef unsigned short u16;
typedef unsigned int u32;

#define B_ 4
#define S_ 1024
#define D_ 1024
#define H_ 16
#define DH_ 64
#define FF_ 4096
#define M_ 4096
#define SCALE_ 0.125f

typedef __attribute__((ext_vector_type(8))) __bf16 bf16x8;
typedef __attribute__((ext_vector_type(4))) float f32x4;

__device__ __forceinline__ f32x4 mfma16(bf16x8 a, bf16x8 b, f32x4 c) {
  return __builtin_amdgcn_mfma_f32_16x16x32_bf16(a, b, c, 0, 0, 0);
}

// native converts -> compiler emits v_cvt_pk_bf16_f32 (catalog m240)
__device__ __forceinline__ u16 f2bf(float x) {
  union { __bf16 h; u16 u; } cv; cv.h = (__bf16)x; return cv.u;
}
__device__ __forceinline__ float bf2f(u16 u) {
  union { u32 u; float f; } cv; cv.u = ((u32)u) << 16; return cv.f;
}
__device__ __forceinline__ u32 packbf2(float a, float b) {
  union { u32 u; __bf16 h[2]; } pk;
  pk.h[0] = (__bf16)a; pk.h[1] = (__bf16)b;
  return pk.u;
}
__device__ __forceinline__ float gelu_exact(float x) {
  return 0.5f * x * (1.f + erff(x * 0.7071067811865475f));
}
__device__ __forceinline__ void gload16(const void* g, void* l) {
  __builtin_amdgcn_global_load_lds((__attribute__((address_space(1))) void*)(g),
                                   (__attribute__((address_space(3))) void*)(l),
                                   16, 0, 0);
}

// ===========================================================================
// 128x128 GEMM, 4 waves (2x2), BK=64, dbuf 64KiB LDS — round-6 schedule.
// EPI: 0 = permuted bf16 -> [ts][B,H,S,DH], ts==0 plane scaled 0.125
//      1 = f32 out = res + acc + bias (in-place out==res elementwise-safe)
//      5 = permuted bf16, NO scale (KV fused store)
// ===========================================================================
template<int EPI>
__global__ __launch_bounds__(256, 2) void gemm128(
    const u16* __restrict__ A, const u16* __restrict__ BT,
    const float* __restrict__ bias, const float* __restrict__ res,
    void* __restrict__ out, int M, int N, int K, int ktiles)
{
  __shared__ u16 As[2][128 * 64];
  __shared__ u16 Bs[2][128 * 64];

  const int tid = threadIdx.x;
  const int wave = tid >> 6, lane = tid & 63;
  const int wm = wave >> 1, wn = wave & 1;
  const int qi = lane & 15, g = lane >> 4;

  const int gx = N >> 7;
  const int nwg = gx * (M >> 7);
  int id = blockIdx.y * gridDim.x + blockIdx.x;
  id = (id & 7) * (nwg >> 3) + (id >> 3);      // XCD swizzle (nwg % 8 == 0)
  const int m0 = (id / gx) << 7, n0 = (id % gx) << 7;

  const int NT = ktiles;
  const int kbase = blockIdx.z * ktiles * 64;

  const int r0 = tid >> 3;
  const int scol = (((tid & 7) ^ ((tid >> 3) & 7)) << 3);
  const int swb = wave << 6;

  f32x4 acc[4][4];
#pragma unroll
  for (int i = 0; i < 4; ++i)
#pragma unroll
    for (int j = 0; j < 4; ++j)
      acc[i][j] = (f32x4){0.f, 0.f, 0.f, 0.f};

#define STAGE_A(t, h, b) {                                                  \
    const int tt = (t) >= NT ? (t) - NT : (t);                              \
    _Pragma("unroll")                                                       \
    for (int i = 0; i < 2; ++i) {                                           \
      const int r = (h) * 64 + i * 32 + r0;                                 \
      gload16(A + (size_t)(m0 + r) * K + kbase + tt * 64 + scol,            \
              &As[b][(h) * 4096 + (i * 256 + swb) * 8]);                    \
    } }
#define STAGE_B(t, h, b) {                                                  \
    const int tt = (t) >= NT ? (t) - NT : (t);                              \
    _Pragma("unroll")                                                       \
    for (int i = 0; i < 2; ++i) {                                           \
      const int r = (h) * 64 + i * 32 + r0;                                 \
      gload16(BT + (size_t)(n0 + r) * K + kbase + tt * 64 + scol,           \
              &Bs[b][(h) * 4096 + (i * 256 + swb) * 8]);                    \
    } }

  bf16x8 af[4][2], bfr[4][2];

#define RD_ALL(b)                                                            \
  _Pragma("unroll") for (int mi = 0; mi < 4; ++mi)                           \
  _Pragma("unroll") for (int kk = 0; kk < 2; ++kk) {                         \
    const int row = wm * 64 + mi * 16 + qi;                                  \
    const int cb = ((kk * 64 + (g << 4)) ^ ((qi & 7) << 4));                 \
    af[mi][kk] = *(const bf16x8*)((const char*)&As[b][0] + row * 128 + cb);  \
  }                                                                          \
  _Pragma("unroll") for (int ni = 0; ni < 4; ++ni)                           \
  _Pragma("unroll") for (int kk = 0; kk < 2; ++kk) {                         \
    const int row = wn * 64 + ni * 16 + qi;                                  \
    const int cb = ((kk * 64 + (g << 4)) ^ ((qi & 7) << 4));                 \
    bfr[ni][kk] = *(const bf16x8*)((const char*)&Bs[b][0] + row * 128 + cb); \
  }

#define HALF(milo)                                                           \
  _Pragma("unroll") for (int mi = (milo); mi < (milo) + 2; ++mi)             \
  _Pragma("unroll") for (int ni = 0; ni < 4; ++ni)                           \
  _Pragma("unroll") for (int kk = 0; kk < 2; ++kk)                           \
    acc[mi][ni] = mfma16(af[mi][kk], bfr[ni][kk], acc[mi][ni]);

#define BAR() __builtin_amdgcn_s_barrier()
#define LGKM0() { asm volatile("s_waitcnt lgkmcnt(0)" ::: "memory");         \
                  __builtin_amdgcn_sched_barrier(0); }
#define VM8() asm volatile("s_waitcnt vmcnt(8)" ::: "memory")
#define PRIO(x) __builtin_amdgcn_s_setprio(x)

  STAGE_A(0, 0, 0); STAGE_A(0, 1, 0); STAGE_B(0, 0, 0); STAGE_B(0, 1, 0);
  STAGE_A(1, 0, 1); STAGE_A(1, 1, 1); STAGE_B(1, 0, 1); STAGE_B(1, 1, 1);
  VM8();
  BAR();

  const int NI = NT >> 1;
  for (int it = 0; it < NI; ++it) {
    const int k = it * 2;
    RD_ALL(0); LGKM0();
    BAR();
    STAGE_A(k + 2, 0, 0); STAGE_A(k + 2, 1, 0);
    PRIO(1); HALF(0); PRIO(0);
    STAGE_B(k + 2, 0, 0); STAGE_B(k + 2, 1, 0);
    PRIO(1); HALF(2); PRIO(0);
    VM8();
    BAR();
    RD_ALL(1); LGKM0();
    BAR();
    STAGE_A(k + 3, 0, 1); STAGE_A(k + 3, 1, 1);
    PRIO(1); HALF(0); PRIO(0);
    STAGE_B(k + 3, 0, 1); STAGE_B(k + 3, 1, 1);
    PRIO(1); HALF(2); PRIO(0);
    VM8();
    BAR();
  }

#pragma unroll
  for (int mi = 0; mi < 4; ++mi) {
#pragma unroll
    for (int ni = 0; ni < 4; ++ni) {
#pragma unroll
      for (int r = 0; r < 4; ++r) {
        const int m = m0 + wm * 64 + mi * 16 + g * 4 + r;
        const int n = n0 + wn * 64 + ni * 16 + qi;
        float v = acc[mi][ni][r];
        if (EPI == 0 || EPI == 5) {
          const int ts = n >> 10, b = m >> 10, s = m & 1023;
          const int hh = (n >> 6) & 15, dh = n & 63;
          if (EPI == 0 && ts == 0) v *= SCALE_;
          ((u16*)out)[(size_t)ts * (B_ * H_ * S_ * DH_) +
                      (((size_t)(b * H_ + hh) * S_) + s) * DH_ + dh] = f2bf(v);
        } else {
          const size_t idx = (size_t)m * N + n;
          ((float*)out)[idx] = res[idx] + v + bias[n];
        }
      }
    }
  }
#undef STAGE_A
#undef STAGE_B
#undef RD_ALL
#undef HALF
#undef BAR
#undef LGKM0
#undef VM8
#undef PRIO
}

// ===========================================================================
// Merged GEGLU FF1 — round-14 proven version (best measured: 78 µs):
// single-buffer 48 KiB LDS, 2-D XCD ownership map, __launch_bounds__(256,2).
// Do NOT raise min-waves bound (round-12 spill) or deep-pipeline B (round-15).
// ===========================================================================
__global__ __launch_bounds__(256, 2) void ffgeglu(
    const u16* __restrict__ A, const u16* __restrict__ BTh,
    const u16* __restrict__ BTg, const float* __restrict__ bias,
    u16* __restrict__ out)
{
  __shared__ u16 As[128 * 64];
  __shared__ u16 Bhs[128 * 64];
  __shared__ u16 Bgs[128 * 64];

  const int tid = threadIdx.x;
  const int wave = tid >> 6, lane = tid & 63;
  const int wm = wave >> 1, wn = wave & 1;
  const int qi = lane & 15, g = lane >> 4;

  // 2-D XCD ownership: XCD (cm,cn) in 2x4 owns a 16m x 8n tile rectangle.
  const int orig = blockIdx.y * gridDim.x + blockIdx.x;   // 1024 blocks
  const int c = orig & 7, j = orig >> 3;
  const int cm = c >> 2, cn = c & 3;
  const int jm = j & 15, jn = j >> 4;
  const int m0 = (cm * 16 + jm) << 7;
  const int n0 = (cn * 8 + jn) << 7;
  const int K = 1024;

  const int r0 = tid >> 3;
  const int scol = (((tid & 7) ^ ((tid >> 3) & 7)) << 3);
  const int swb = wave << 6;

  f32x4 acch[4][4], accg[4][4];
#pragma unroll
  for (int i = 0; i < 4; ++i)
#pragma unroll
    for (int j2 = 0; j2 < 4; ++j2) {
      acch[i][j2] = (f32x4){0.f, 0.f, 0.f, 0.f};
      accg[i][j2] = (f32x4){0.f, 0.f, 0.f, 0.f};
    }

  for (int t = 0; t < 16; ++t) {
    if (t) __syncthreads();
#pragma unroll
    for (int i = 0; i < 4; ++i) {
      const int r = i * 32 + r0;
      gload16(A + (size_t)(m0 + r) * K + t * 64 + scol,
              &As[(i * 256 + swb) * 8]);
    }
#pragma unroll
    for (int i = 0; i < 4; ++i) {
      const int r = i * 32 + r0;
      gload16(BTh + (size_t)(n0 + r) * K + t * 64 + scol,
              &Bhs[(i * 256 + swb) * 8]);
    }
#pragma unroll
    for (int i = 0; i < 4; ++i) {
      const int r = i * 32 + r0;
      gload16(BTg + (size_t)(n0 + r) * K + t * 64 + scol,
              &Bgs[(i * 256 + swb) * 8]);
    }
    __syncthreads();

    bf16x8 af[4][2], bfr[4][2];
#pragma unroll
    for (int mi = 0; mi < 4; ++mi)
#pragma unroll
      for (int kk = 0; kk < 2; ++kk) {
        const int row = wm * 64 + mi * 16 + qi;
        const int cb = ((kk * 64 + (g << 4)) ^ ((qi & 7) << 4));
        af[mi][kk] = *(const bf16x8*)((const char*)&As[0] + row * 128 + cb);
      }
    // ---- h half ----
#pragma unroll
    for (int ni = 0; ni < 4; ++ni)
#pragma unroll
      for (int kk = 0; kk < 2; ++kk) {
        const int row = wn * 64 + ni * 16 + qi;
        const int cb = ((kk * 64 + (g << 4)) ^ ((qi & 7) << 4));
        bfr[ni][kk] = *(const bf16x8*)((const char*)&Bhs[0] + row * 128 + cb);
      }
#pragma unroll
    for (int mi = 0; mi < 4; ++mi)
#pragma unroll
      for (int ni = 0; ni < 4; ++ni)
#pragma unroll
        for (int kk = 0; kk < 2; ++kk)
          acch[mi][ni] = mfma16(af[mi][kk], bfr[ni][kk], acch[mi][ni]);
    // ---- gate half (bfr reused) ----
#pragma unroll
    for (int ni = 0; ni < 4; ++ni)
#pragma unroll
      for (int kk = 0; kk < 2; ++kk) {
        const int row = wn * 64 + ni * 16 + qi;
        const int cb = ((kk * 64 + (g << 4)) ^ ((qi & 7) << 4));
        bfr[ni][kk] = *(const bf16x8*)((const char*)&Bgs[0] + row * 128 + cb);
      }
#pragma unroll
    for (int mi = 0; mi < 4; ++mi)
#pragma unroll
      for (int ni = 0; ni < 4; ++ni)
#pragma unroll
        for (int kk = 0; kk < 2; ++kk)
          accg[mi][ni] = mfma16(af[mi][kk], bfr[ni][kk], accg[mi][ni]);
  }

#pragma unroll
  for (int mi = 0; mi < 4; ++mi) {
#pragma unroll
    for (int ni = 0; ni < 4; ++ni) {
#pragma unroll
      for (int r = 0; r < 4; ++r) {
        const int m = m0 + wm * 64 + mi * 16 + g * 4 + r;
        const int n = n0 + wn * 64 + ni * 16 + qi;
        const float hv = acch[mi][ni][r] + bias[n];
        const float gv = accg[mi][ni][r] + bias[FF_ + n];
        out[(size_t)m * FF_ + n] = f2bf(hv * gelu_exact(gv));
      }
    }
  }
}

// ---------------------------------------------------------------------------
// Flash attention. Q pre-scaled by 0.125. Fixed-max softmax. 4 waves x 16 q.
// NEW: K/V staged direct-to-LDS via global_load_lds (T2 both-sides swizzle:
// pre-swizzled global source col + XOR on read byte offset; linear stride-64
// LDS, rows 16k+qi so row&7 == qi&7). Ps keeps its padded layout.
// ---------------------------------------------------------------------------
template<bool MASKED>
__global__ __launch_bounds__(256, 4) void attn_kernel(
    const u16* __restrict__ Q, const u16* __restrict__ Kb,
    const u16* __restrict__ VT, const float* __restrict__ bias,
    u16* __restrict__ O, int S, int T)
{
  __shared__ u16 Ks[64 * 64];        // [t][dh] stride 64, T2-swizzled
  __shared__ u16 VTs[64 * 64];       // [dh][t] stride 64, T2-swizzled
  __shared__ u16 Ps[4][16 * 72];     // per-wave P^T [q][t] (padded, unchanged)
  __shared__ float biasS[64];

  const int bh = blockIdx.y;
  const int b = bh >> 4, h = bh & 15;
  const int tid = threadIdx.x;
  const int wave = tid >> 6, lane = tid & 63;
  const int g = lane >> 4, qi = lane & 15;
  const int q0w = blockIdx.x * 64 + wave * 16;

  const u16* Qb = Q + (size_t)bh * S * DH_;
  const u16* Kg = Kb + (size_t)bh * T * DH_;
  const u16* Vg = VT + (size_t)bh * DH_ * T;

  // staging constants (same pattern as gemm128)
  const int r0 = tid >> 3;                                  // 0..31
  const int scol = (((tid & 7) ^ ((tid >> 3) & 7)) << 3);   // elements
  const int swb = wave << 6;

  bf16x8 qf[2];
  qf[0] = *(const bf16x8*)&Qb[(q0w + qi) * DH_ + g * 8];
  qf[1] = *(const bf16x8*)&Qb[(q0w + qi) * DH_ + 32 + g * 8];

  f32x4 acc[4];
#pragma unroll
  for (int i = 0; i < 4; ++i) acc[i] = (f32x4){0.f, 0.f, 0.f, 0.f};
  float l_run = 1e-30f;

  u16* Pw = &Ps[wave][0];

  for (int t0 = 0; t0 < T; t0 += 64) {
    __syncthreads();
#pragma unroll
    for (int i = 0; i < 2; ++i) {
      const int r = i * 32 + r0;
      gload16(Kg + (size_t)(t0 + r) * DH_ + scol, &Ks[(i * 256 + swb) * 8]);
      gload16(Vg + (size_t)r * T + t0 + scol, &VTs[(i * 256 + swb) * 8]);
    }
    if (MASKED && tid < 64) biasS[tid] = bias[b * T + t0 + tid];
    __syncthreads();   // compiler drains vmcnt(0)+lgkmcnt here

    // S^T[t][q] = K · Q^T  (Q pre-scaled); swizzled K read
    f32x4 sacc[4];
#pragma unroll
    for (int nt = 0; nt < 4; ++nt) sacc[nt] = (f32x4){0.f, 0.f, 0.f, 0.f};
#pragma unroll
    for (int kk = 0; kk < 2; ++kk) {
#pragma unroll
      for (int nt = 0; nt < 4; ++nt) {
        const int row = nt * 16 + qi;
        const int cb = ((kk * 64 + (g << 4)) ^ ((qi & 7) << 4));
        bf16x8 kf = *(const bf16x8*)((const char*)&Ks[0] + row * 128 + cb);
        sacc[nt] = mfma16(kf, qf[kk], sacc[nt]);
      }
    }
    float p[4][4];
    float lsum = 0.f;
#pragma unroll
    for (int nt = 0; nt < 4; ++nt)
#pragma unroll
      for (int r = 0; r < 4; ++r) {
        float v = sacc[nt][r];
        if (MASKED) v += biasS[nt * 16 + g * 4 + r];
        const float e = __expf(v);
        p[nt][r] = e;
        lsum += e;
      }
    lsum += __shfl_xor(lsum, 16);
    lsum += __shfl_xor(lsum, 32);
    l_run += lsum;

#pragma unroll
    for (int nt = 0; nt < 4; ++nt) {
      uint2 w;
      w.x = packbf2(p[nt][0], p[nt][1]);
      w.y = packbf2(p[nt][2], p[nt][3]);
      *(uint2*)&Pw[qi * 72 + nt * 16 + g * 4] = w;
    }

    // PV: out^T[dh][q] += V^T · P^T ; swizzled V read
#pragma unroll
    for (int kk = 0; kk < 2; ++kk) {
      bf16x8 pf = *(const bf16x8*)&Pw[qi * 72 + kk * 32 + g * 8];
#pragma unroll
      for (int ndh = 0; ndh < 4; ++ndh) {
        const int row = ndh * 16 + qi;
        const int cb = ((kk * 64 + (g << 4)) ^ ((qi & 7) << 4));
        bf16x8 vf = *(const bf16x8*)((const char*)&VTs[0] + row * 128 + cb);
        acc[ndh] = mfma16(vf, pf, acc[ndh]);
      }
    }
  }

  const float inv = 1.f / l_run;
  const int qg = q0w + qi;
#pragma unroll
  for (int ndh = 0; ndh < 4; ++ndh) {
    uint2 w;
    w.x = packbf2(acc[ndh][0] * inv, acc[ndh][1] * inv);
    w.y = packbf2(acc[ndh][2] * inv, acc[ndh][3] * inv);
    *(uint2*)&O[(size_t)(b * S_ + qg) * D_ + h * DH_ + ndh * 16 + g * 4] = w;
  }
}

// ---------------------------------------------------------------------------
__global__ __launch_bounds__(256) void ln_kernel(
    const float* __restrict__ x, const float* __restrict__ gg,
    const float* __restrict__ bb, u16* __restrict__ out)
{
  __shared__ float red[8];
  const int row = blockIdx.x, tid = threadIdx.x;
  const float4 v = ((const float4*)(x + (size_t)row * D_))[tid];
  float s = v.x + v.y + v.z + v.w;
  float sq = v.x * v.x + v.y * v.y + v.z * v.z + v.w * v.w;
#pragma unroll
  for (int m = 32; m; m >>= 1) {
    s += __shfl_xor(s, m);
    sq += __shfl_xor(sq, m);
  }
  const int wave = tid >> 6, lane = tid & 63;
  if (lane == 0) { red[wave * 2] = s; red[wave * 2 + 1] = sq; }
  __syncthreads();
  const float St = red[0] + red[2] + red[4] + red[6];
  const float SQt = red[1] + red[3] + red[5] + red[7];
  const float mean = St * (1.f / 1024.f);
  float var = SQt * (1.f / 1024.f) - mean * mean;
  var = fmaxf(var, 0.f);
  const float rinv = rsqrtf(var + 1e-12f);
  const float4 g4 = ((const float4*)gg)[tid];
  const float4 b4 = ((const float4*)bb)[tid];
  uint2 o;
  o.x = packbf2((v.x - mean) * rinv * g4.x + b4.x, (v.y - mean) * rinv * g4.y + b4.y);
  o.y = packbf2((v.z - mean) * rinv * g4.z + b4.z, (v.w - mean) * rinv * g4.w + b4.w);
  ((uint2*)(out + (size_t)row * D_))[tid] = o;
}

__global__ __launch_bounds__(256) void transpose_w(
    const float* __restrict__ in, u16* __restrict__ out, int K, int N)
{
  __shared__ float tile[32][33];
  const int tx = threadIdx.x & 31, ty = threadIdx.x >> 5;
  const int k0 = blockIdx.y * 32, n0 = blockIdx.x * 32;
#pragma unroll
  for (int j = 0; j < 4; ++j)
    tile[ty + 8 * j][tx] = in[(size_t)(k0 + ty + 8 * j) * N + n0 + tx];
  __syncthreads();
#pragma unroll
  for (int j = 0; j < 4; ++j)
    out[(size_t)(n0 + ty + 8 * j) * K + k0 + tx] = f2bf(tile[tx][ty + 8 * j]);
}

__global__ __launch_bounds__(256) void transpose_w8(
    const float* __restrict__ w0, const float* __restrict__ w1,
    const float* __restrict__ w2, const float* __restrict__ w3,
    const float* __restrict__ w4, const float* __restrict__ w5,
    const float* __restrict__ w6, const float* __restrict__ w7,
    u16* __restrict__ outbase)
{
  __shared__ float tile[32][33];
  const float* srcs[8] = {w0, w1, w2, w3, w4, w5, w6, w7};
  const float* in = srcs[blockIdx.z];
  u16* out = outbase + (size_t)blockIdx.z * 1024 * 1024;
  const int tx = threadIdx.x & 31, ty = threadIdx.x >> 5;
  const int k0 = blockIdx.y * 32, n0 = blockIdx.x * 32;
#pragma unroll
  for (int j = 0; j < 4; ++j)
    tile[ty + 8 * j][tx] = in[(size_t)(k0 + ty + 8 * j) * 1024 + n0 + tx];
  __syncthreads();
#pragma unroll
  for (int j = 0; j < 4; ++j)
    out[(size_t)(n0 + ty + 8 * j) * 1024 + k0 + tx] = f2bf(tile[tx][ty + 8 * j]);
}

__global__ __launch_bounds__(256) void transpose_v(
    const u16* __restrict__ in, u16* __restrict__ out, int T)
{
  __shared__ u16 tile[32][33];
  const int tx = threadIdx.x & 31, ty = threadIdx.x >> 5;
  const int bh = blockIdx.z;
  const int t0 = blockIdx.x * 32, d0 = blockIdx.y * 32;
  const u16* ib = in + (size_t)bh * T * DH_;
  u16* ob = out + (size_t)bh * DH_ * T;
#pragma unroll
  for (int j = 0; j < 4; ++j)
    tile[ty + 8 * j][tx] = ib[(size_t)(t0 + ty + 8 * j) * DH_ + d0 + tx];
  __syncthreads();
#pragma unroll
  for (int j = 0; j < 4; ++j)
    ob[(size_t)(d0 + ty + 8 * j) * T + t0 + tx] = tile[tx][ty + 8 * j];
}

__global__ void cvt_bf16(const float* __restrict__ in, u16* __restrict__ out, int n4)
{
  const int i = blockIdx.x * blockDim.x + threadIdx.x;
  if (i < n4) {
    const float4 v = ((const float4*)in)[i];
    uint2 o;
    o.x = packbf2(v.x, v.y);
    o.y = packbf2(v.z, v.w);
    ((uint2*)out)[i] = o;
  }
}

__global__ void mask_bias(const int* __restrict__ mask, float* __restrict__ bias, int n)
{
  const int i = blockIdx.x * blockDim.x + threadIdx.x;
  if (i < n) bias[i] = mask[i] ? 0.f : -1e30f;
}

// ---------------------------------------------------------------------------
extern "C" void kernel_launch(void* const* d_in, const int* in_sizes, int n_in,
                              void* d_out, int out_size, void* d_ws, size_t ws_size,
                              hipStream_t stream)
{
  (void)in_sizes; (void)n_in; (void)out_size; (void)ws_size;
  const float* hidden = (const float*)d_in[0];
  const float* ctx    = (const float*)d_in[1];
  const int*   mask   = (const int*)d_in[2];
  const float* g1 = (const float*)d_in[3];
  const float* b1 = (const float*)d_in[4];
  const float* g2 = (const float*)d_in[5];
  const float* b2 = (const float*)d_in[6];
  const float* g3 = (const float*)d_in[7];
  const float* b3 = (const float*)d_in[8];
  const float* Wq1 = (const float*)d_in[9];
  const float* Wk1 = (const float*)d_in[10];
  const float* Wv1 = (const float*)d_in[11];
  const float* Wo1 = (const float*)d_in[12];
  const float* bo1 = (const float*)d_in[13];
  const float* Wq2 = (const float*)d_in[14];
  const float* Wk2 = (const float*)d_in[15];
  const float* Wv2 = (const float*)d_in[16];
  const float* Wo2 = (const float*)d_in[17];
  const float* bo2 = (const float*)d_in[18];
  const float* Wff1 = (const float*)d_in[19];
  const float* bff1 = (const float*)d_in[20];
  const float* Wff2 = (const float*)d_in[21];
  const float* bff2 = (const float*)d_in[22];

  char* ws = (char*)d_ws;
  size_t off = 0;
  auto alloc = [&](size_t bytes) -> void* {
    void* p = ws + off;
    off += (bytes + 255) & ~(size_t)255;
    return p;
  };
  // WqT1..WoT2: 8 CONTIGUOUS 2MB blocks (transpose_w8 target).
  u16* WqT1  = (u16*)alloc((size_t)1024 * 1024 * 2);
  u16* WkT1  = (u16*)alloc((size_t)1024 * 1024 * 2);
  u16* WvT1  = (u16*)alloc((size_t)1024 * 1024 * 2);
  u16* WoT1  = (u16*)alloc((size_t)1024 * 1024 * 2);
  u16* WqT2  = (u16*)alloc((size_t)1024 * 1024 * 2);
  u16* WkT2  = (u16*)alloc((size_t)1024 * 1024 * 2);
  u16* WvT2  = (u16*)alloc((size_t)1024 * 1024 * 2);
  u16* WoT2  = (u16*)alloc((size_t)1024 * 1024 * 2);
  u16* Wff1T = (u16*)alloc((size_t)8192 * 1024 * 2);
  u16* Wff2T = (u16*)alloc((size_t)1024 * 4096 * 2);
  u16* nbuf  = (u16*)alloc((size_t)M_ * D_ * 2);
  u16* hgbuf = (u16*)alloc((size_t)M_ * FF_ * 2);
  u16* qbuf  = (u16*)alloc((size_t)M_ * D_ * 2);
  u16* kbuf  = (u16*)alloc((size_t)M_ * D_ * 2);
  u16* vbuf  = (u16*)alloc((size_t)M_ * D_ * 2);
  u16* vtbuf = (u16*)alloc((size_t)M_ * D_ * 2);
  u16* attnb = (u16*)alloc((size_t)M_ * D_ * 2);
  u16* ctxb  = (u16*)alloc((size_t)M_ * D_ * 2);
  float* biasw = (float*)alloc((size_t)B_ * S_ * 4);
  float* hres = (float*)d_out;   // residual chain lives in d_out (f32)
  (void)WkT1; (void)WvT1; (void)WkT2; (void)WvT2; (void)WoT2;

  const dim3 blk(256);
  const dim3 gW8(32, 32, 8);
  const dim3 gQKV(24, 32);       // N=3072 -> 768 blocks
  const dim3 gKV(16, 32);        // N=2048 -> 512 blocks
  const dim3 gP(8, 32);          // N=1024 -> 256 blocks (direct)
  const dim3 gFF(32, 32);        // merged GEGLU: 1024 blocks
  const dim3 gA(16, 64);
  const dim3 gV(32, 2, 64);

  // weight prep (batched)
  transpose_w8<<<gW8, blk, 0, stream>>>(Wq1, Wk1, Wv1, Wo1, Wq2, Wk2, Wv2, Wo2,
                                        WqT1);
  transpose_w<<<dim3(256, 32), blk, 0, stream>>>(Wff1, Wff1T, 1024, 8192);
  transpose_w<<<dim3(32, 128), blk, 0, stream>>>(Wff2, Wff2T, 4096, 1024);
  cvt_bf16<<<dim3(4096), blk, 0, stream>>>(ctx, ctxb, 1048576);
  mask_bias<<<dim3(16), blk, 0, stream>>>(mask, biasw, B_ * S_);

  // --- self attention ---
  ln_kernel<<<dim3(M_), blk, 0, stream>>>(hidden, g1, b1, nbuf);
  gemm128<0><<<gQKV, blk, 0, stream>>>(nbuf, WqT1, nullptr, nullptr,
                                       qbuf, M_, 3072, 1024, 16);
  transpose_v<<<gV, blk, 0, stream>>>(vbuf, vtbuf, 1024);
  attn_kernel<false><<<gA, blk, 0, stream>>>(qbuf, kbuf, vtbuf, nullptr, attnb,
                                             S_, S_);
  // h1 = hidden + attnO + bo1 (direct, f32 into d_out)
  gemm128<1><<<gP, blk, 0, stream>>>(attnb, WoT1, bo1, hidden,
                                     hres, M_, 1024, 1024, 16);
  ln_kernel<<<dim3(M_), blk, 0, stream>>>(hres, g2, b2, nbuf);

  // --- cross attention ---
  gemm128<0><<<gP, blk, 0, stream>>>(nbuf, WqT2, nullptr, nullptr,
                                     qbuf, M_, 1024, 1024, 16);   // Q2 (scaled)
  gemm128<5><<<gKV, blk, 0, stream>>>(ctxb, WkT2, nullptr, nullptr,
                                      kbuf, M_, 2048, 1024, 16);  // K2,V2 fused
  transpose_v<<<gV, blk, 0, stream>>>(vbuf, vtbuf, 1024);
  attn_kernel<true><<<gA, blk, 0, stream>>>(qbuf, kbuf, vtbuf, biasw, attnb,
                                            S_, S_);
  // h2 = h1 + attnO + bo2 (in-place on d_out; elementwise-safe)
  gemm128<1><<<gP, blk, 0, stream>>>(attnb, WoT2, bo2, hres,
                                     hres, M_, 1024, 1024, 16);
  ln_kernel<<<dim3(M_), blk, 0, stream>>>(hres, g3, b3, nbuf);

  // --- GEGLU FF ---
  ffgeglu<<<gFF, blk, 0, stream>>>(nbuf, Wff1T, Wff1T + (size_t)FF_ * 1024,
                                   bff1, hgbuf);
  // out = h2 + (hg @ Wff2) + bff2 (direct, in-place on d_out)
  gemm128<1><<<gP, blk, 0, stream>>>(hgbuf, Wff2T, bff2, hres,
                                     hres, M_, 1024, 4096, 64);
}

// Round 18
// 340.361 us; speedup vs baseline: 1.0915x; 1.0098x over previous
//
#include <hip/hip_runtime.h>

typedef unsigned short u16;
typedef unsigned int u32;

#define B_ 4
#define S_ 1024
#define D_ 1024
#define H_ 16
#define DH_ 64
#define FF_ 4096
#define M_ 4096
#define SCALE_ 0.125f

typedef __attribute__((ext_vector_type(8))) __bf16 bf16x8;
typedef __attribute__((ext_vector_type(4))) float f32x4;

__device__ __forceinline__ f32x4 mfma16(bf16x8 a, bf16x8 b, f32x4 c) {
  return __builtin_amdgcn_mfma_f32_16x16x32_bf16(a, b, c, 0, 0, 0);
}

// native converts -> compiler emits v_cvt_pk_bf16_f32 (catalog m240)
__device__ __forceinline__ u16 f2bf(float x) {
  union { __bf16 h; u16 u; } cv; cv.h = (__bf16)x; return cv.u;
}
__device__ __forceinline__ float bf2f(u16 u) {
  union { u32 u; float f; } cv; cv.u = ((u32)u) << 16; return cv.f;
}
__device__ __forceinline__ u32 packbf2(float a, float b) {
  union { u32 u; __bf16 h[2]; } pk;
  pk.h[0] = (__bf16)a; pk.h[1] = (__bf16)b;
  return pk.u;
}
__device__ __forceinline__ float gelu_exact(float x) {
  return 0.5f * x * (1.f + erff(x * 0.7071067811865475f));
}
__device__ __forceinline__ void gload16(const void* g, void* l) {
  __builtin_amdgcn_global_load_lds((__attribute__((address_space(1))) void*)(g),
                                   (__attribute__((address_space(3))) void*)(l),
                                   16, 0, 0);
}

// ===========================================================================
// 128x128 GEMM, 4 waves (2x2), BK=64, dbuf 64KiB LDS — round-6 schedule.
// EPI: 0 = permuted bf16 -> [ts][B,H,S,DH], ts==0 plane scaled 0.125
//      1 = f32 out = res + acc + bias (in-place out==res elementwise-safe)
//      5 = permuted bf16, NO scale (KV fused store)
// ===========================================================================
template<int EPI>
__global__ __launch_bounds__(256, 2) void gemm128(
    const u16* __restrict__ A, const u16* __restrict__ BT,
    const float* __restrict__ bias, const float* __restrict__ res,
    void* __restrict__ out, int M, int N, int K, int ktiles)
{
  __shared__ u16 As[2][128 * 64];
  __shared__ u16 Bs[2][128 * 64];

  const int tid = threadIdx.x;
  const int wave = tid >> 6, lane = tid & 63;
  const int wm = wave >> 1, wn = wave & 1;
  const int qi = lane & 15, g = lane >> 4;

  const int gx = N >> 7;
  const int nwg = gx * (M >> 7);
  int id = blockIdx.y * gridDim.x + blockIdx.x;
  id = (id & 7) * (nwg >> 3) + (id >> 3);      // XCD swizzle (nwg % 8 == 0)
  const int m0 = (id / gx) << 7, n0 = (id % gx) << 7;

  const int NT = ktiles;
  const int kbase = blockIdx.z * ktiles * 64;

  const int r0 = tid >> 3;
  const int scol = (((tid & 7) ^ ((tid >> 3) & 7)) << 3);
  const int swb = wave << 6;

  f32x4 acc[4][4];
#pragma unroll
  for (int i = 0; i < 4; ++i)
#pragma unroll
    for (int j = 0; j < 4; ++j)
      acc[i][j] = (f32x4){0.f, 0.f, 0.f, 0.f};

#define STAGE_A(t, h, b) {                                                  \
    const int tt = (t) >= NT ? (t) - NT : (t);                              \
    _Pragma("unroll")                                                       \
    for (int i = 0; i < 2; ++i) {                                           \
      const int r = (h) * 64 + i * 32 + r0;                                 \
      gload16(A + (size_t)(m0 + r) * K + kbase + tt * 64 + scol,            \
              &As[b][(h) * 4096 + (i * 256 + swb) * 8]);                    \
    } }
#define STAGE_B(t, h, b) {                                                  \
    const int tt = (t) >= NT ? (t) - NT : (t);                              \
    _Pragma("unroll")                                                       \
    for (int i = 0; i < 2; ++i) {                                           \
      const int r = (h) * 64 + i * 32 + r0;                                 \
      gload16(BT + (size_t)(n0 + r) * K + kbase + tt * 64 + scol,           \
              &Bs[b][(h) * 4096 + (i * 256 + swb) * 8]);                    \
    } }

  bf16x8 af[4][2], bfr[4][2];

#define RD_ALL(b)                                                            \
  _Pragma("unroll") for (int mi = 0; mi < 4; ++mi)                           \
  _Pragma("unroll") for (int kk = 0; kk < 2; ++kk) {                         \
    const int row = wm * 64 + mi * 16 + qi;                                  \
    const int cb = ((kk * 64 + (g << 4)) ^ ((qi & 7) << 4));                 \
    af[mi][kk] = *(const bf16x8*)((const char*)&As[b][0] + row * 128 + cb);  \
  }                                                                          \
  _Pragma("unroll") for (int ni = 0; ni < 4; ++ni)                           \
  _Pragma("unroll") for (int kk = 0; kk < 2; ++kk) {                         \
    const int row = wn * 64 + ni * 16 + qi;                                  \
    const int cb = ((kk * 64 + (g << 4)) ^ ((qi & 7) << 4));                 \
    bfr[ni][kk] = *(const bf16x8*)((const char*)&Bs[b][0] + row * 128 + cb); \
  }

#define HALF(milo)                                                           \
  _Pragma("unroll") for (int mi = (milo); mi < (milo) + 2; ++mi)             \
  _Pragma("unroll") for (int ni = 0; ni < 4; ++ni)                           \
  _Pragma("unroll") for (int kk = 0; kk < 2; ++kk)                           \
    acc[mi][ni] = mfma16(af[mi][kk], bfr[ni][kk], acc[mi][ni]);

#define BAR() __builtin_amdgcn_s_barrier()
#define LGKM0() { asm volatile("s_waitcnt lgkmcnt(0)" ::: "memory");         \
                  __builtin_amdgcn_sched_barrier(0); }
#define VM8() asm volatile("s_waitcnt vmcnt(8)" ::: "memory")
#define PRIO(x) __builtin_amdgcn_s_setprio(x)

  STAGE_A(0, 0, 0); STAGE_A(0, 1, 0); STAGE_B(0, 0, 0); STAGE_B(0, 1, 0);
  STAGE_A(1, 0, 1); STAGE_A(1, 1, 1); STAGE_B(1, 0, 1); STAGE_B(1, 1, 1);
  VM8();
  BAR();

  const int NI = NT >> 1;
  for (int it = 0; it < NI; ++it) {
    const int k = it * 2;
    RD_ALL(0); LGKM0();
    BAR();
    STAGE_A(k + 2, 0, 0); STAGE_A(k + 2, 1, 0);
    PRIO(1); HALF(0); PRIO(0);
    STAGE_B(k + 2, 0, 0); STAGE_B(k + 2, 1, 0);
    PRIO(1); HALF(2); PRIO(0);
    VM8();
    BAR();
    RD_ALL(1); LGKM0();
    BAR();
    STAGE_A(k + 3, 0, 1); STAGE_A(k + 3, 1, 1);
    PRIO(1); HALF(0); PRIO(0);
    STAGE_B(k + 3, 0, 1); STAGE_B(k + 3, 1, 1);
    PRIO(1); HALF(2); PRIO(0);
    VM8();
    BAR();
  }

#pragma unroll
  for (int mi = 0; mi < 4; ++mi) {
#pragma unroll
    for (int ni = 0; ni < 4; ++ni) {
#pragma unroll
      for (int r = 0; r < 4; ++r) {
        const int m = m0 + wm * 64 + mi * 16 + g * 4 + r;
        const int n = n0 + wn * 64 + ni * 16 + qi;
        float v = acc[mi][ni][r];
        if (EPI == 0 || EPI == 5) {
          const int ts = n >> 10, b = m >> 10, s = m & 1023;
          const int hh = (n >> 6) & 15, dh = n & 63;
          if (EPI == 0 && ts == 0) v *= SCALE_;
          ((u16*)out)[(size_t)ts * (B_ * H_ * S_ * DH_) +
                      (((size_t)(b * H_ + hh) * S_) + s) * DH_ + dh] = f2bf(v);
        } else {
          const size_t idx = (size_t)m * N + n;
          ((float*)out)[idx] = res[idx] + v + bias[n];
        }
      }
    }
  }
#undef STAGE_A
#undef STAGE_B
#undef RD_ALL
#undef HALF
#undef BAR
#undef LGKM0
#undef VM8
#undef PRIO
}

// ===========================================================================
// Horizontally fused Q2 + KV2 (cross-attention projections): blocks 0..255
// compute Q2 = ln2 @ Wq2 (scaled, -> qbuf permuted); blocks 256..767 compute
// [K2|V2] = ctx @ [Wk2|Wv2] (-> kbuf/vbuf permuted). Both partitions are
// independent (inputs nbuf/ctxb both ready); fusing fills the machine
// (768 blocks vs a 1-block/CU dispatch followed by a 2-block/CU dispatch).
// Same round-6 schedule/LDS/swizzle as gemm128; per-partition XCD swizzle.
// ===========================================================================
__global__ __launch_bounds__(256, 2) void qkv2_fused(
    const u16* __restrict__ Anb, const u16* __restrict__ Wq,
    const u16* __restrict__ Actx, const u16* __restrict__ Wkv,
    u16* __restrict__ qout, u16* __restrict__ kvout)
{
  __shared__ u16 As[2][128 * 64];
  __shared__ u16 Bs[2][128 * 64];

  const int tid = threadIdx.x;
  const int wave = tid >> 6, lane = tid & 63;
  const int wm = wave >> 1, wn = wave & 1;
  const int qi = lane & 15, g = lane >> 4;

  const int bid = blockIdx.x;              // 768 blocks
  const u16* A;  const u16* BT;  u16* out;
  int N, id;
  bool qsc;
  if (bid < 256) { A = Anb;  BT = Wq;  out = qout;  N = 1024; id = bid;       qsc = true;  }
  else           { A = Actx; BT = Wkv; out = kvout; N = 2048; id = bid - 256; qsc = false; }
  const int gx = N >> 7;
  const int nwg = gx * 32;
  id = (id & 7) * (nwg >> 3) + (id >> 3);  // per-partition XCD swizzle
  const int m0 = (id / gx) << 7, n0 = (id % gx) << 7;
  const int K = 1024, NT = 16;

  const int r0 = tid >> 3;
  const int scol = (((tid & 7) ^ ((tid >> 3) & 7)) << 3);
  const int swb = wave << 6;

  f32x4 acc[4][4];
#pragma unroll
  for (int i = 0; i < 4; ++i)
#pragma unroll
    for (int j = 0; j < 4; ++j)
      acc[i][j] = (f32x4){0.f, 0.f, 0.f, 0.f};

#define STAGE_A(t, h, b) {                                                  \
    const int tt = (t) >= NT ? (t) - NT : (t);                              \
    _Pragma("unroll")                                                       \
    for (int i = 0; i < 2; ++i) {                                           \
      const int r = (h) * 64 + i * 32 + r0;                                 \
      gload16(A + (size_t)(m0 + r) * K + tt * 64 + scol,                    \
              &As[b][(h) * 4096 + (i * 256 + swb) * 8]);                    \
    } }
#define STAGE_B(t, h, b) {                                                  \
    const int tt = (t) >= NT ? (t) - NT : (t);                              \
    _Pragma("unroll")                                                       \
    for (int i = 0; i < 2; ++i) {                                           \
      const int r = (h) * 64 + i * 32 + r0;                                 \
      gload16(BT + (size_t)(n0 + r) * K + tt * 64 + scol,                   \
              &Bs[b][(h) * 4096 + (i * 256 + swb) * 8]);                    \
    } }

  bf16x8 af[4][2], bfr[4][2];

#define RD_ALL(b)                                                            \
  _Pragma("unroll") for (int mi = 0; mi < 4; ++mi)                           \
  _Pragma("unroll") for (int kk = 0; kk < 2; ++kk) {                         \
    const int row = wm * 64 + mi * 16 + qi;                                  \
    const int cb = ((kk * 64 + (g << 4)) ^ ((qi & 7) << 4));                 \
    af[mi][kk] = *(const bf16x8*)((const char*)&As[b][0] + row * 128 + cb);  \
  }                                                                          \
  _Pragma("unroll") for (int ni = 0; ni < 4; ++ni)                           \
  _Pragma("unroll") for (int kk = 0; kk < 2; ++kk) {                         \
    const int row = wn * 64 + ni * 16 + qi;                                  \
    const int cb = ((kk * 64 + (g << 4)) ^ ((qi & 7) << 4));                 \
    bfr[ni][kk] = *(const bf16x8*)((const char*)&Bs[b][0] + row * 128 + cb); \
  }

#define HALF(milo)                                                           \
  _Pragma("unroll") for (int mi = (milo); mi < (milo) + 2; ++mi)             \
  _Pragma("unroll") for (int ni = 0; ni < 4; ++ni)                           \
  _Pragma("unroll") for (int kk = 0; kk < 2; ++kk)                           \
    acc[mi][ni] = mfma16(af[mi][kk], bfr[ni][kk], acc[mi][ni]);

#define BAR() __builtin_amdgcn_s_barrier()
#define LGKM0() { asm volatile("s_waitcnt lgkmcnt(0)" ::: "memory");         \
                  __builtin_amdgcn_sched_barrier(0); }
#define VM8() asm volatile("s_waitcnt vmcnt(8)" ::: "memory")
#define PRIO(x) __builtin_amdgcn_s_setprio(x)

  STAGE_A(0, 0, 0); STAGE_A(0, 1, 0); STAGE_B(0, 0, 0); STAGE_B(0, 1, 0);
  STAGE_A(1, 0, 1); STAGE_A(1, 1, 1); STAGE_B(1, 0, 1); STAGE_B(1, 1, 1);
  VM8();
  BAR();

  for (int it = 0; it < 8; ++it) {
    const int k = it * 2;
    RD_ALL(0); LGKM0();
    BAR();
    STAGE_A(k + 2, 0, 0); STAGE_A(k + 2, 1, 0);
    PRIO(1); HALF(0); PRIO(0);
    STAGE_B(k + 2, 0, 0); STAGE_B(k + 2, 1, 0);
    PRIO(1); HALF(2); PRIO(0);
    VM8();
    BAR();
    RD_ALL(1); LGKM0();
    BAR();
    STAGE_A(k + 3, 0, 1); STAGE_A(k + 3, 1, 1);
    PRIO(1); HALF(0); PRIO(0);
    STAGE_B(k + 3, 0, 1); STAGE_B(k + 3, 1, 1);
    PRIO(1); HALF(2); PRIO(0);
    VM8();
    BAR();
  }

  const float sc = qsc ? SCALE_ : 1.f;
#pragma unroll
  for (int mi = 0; mi < 4; ++mi) {
#pragma unroll
    for (int ni = 0; ni < 4; ++ni) {
#pragma unroll
      for (int r = 0; r < 4; ++r) {
        const int m = m0 + wm * 64 + mi * 16 + g * 4 + r;
        const int n = n0 + wn * 64 + ni * 16 + qi;
        const float v = acc[mi][ni][r] * sc;
        const int ts = n >> 10, b = m >> 10, s = m & 1023;
        const int hh = (n >> 6) & 15, dh = n & 63;
        out[(size_t)ts * (B_ * H_ * S_ * DH_) +
            (((size_t)(b * H_ + hh) * S_) + s) * DH_ + dh] = f2bf(v);
      }
    }
  }
#undef STAGE_A
#undef STAGE_B
#undef RD_ALL
#undef HALF
#undef BAR
#undef LGKM0
#undef VM8
#undef PRIO
}

// ===========================================================================
// Merged GEGLU FF1 — round-14 proven version (best measured: 78 µs):
// single-buffer 48 KiB LDS, 2-D XCD ownership map, __launch_bounds__(256,2).
// Do NOT raise min-waves bound (round-12 spill) or deep-pipeline B (round-15).
// ===========================================================================
__global__ __launch_bounds__(256, 2) void ffgeglu(
    const u16* __restrict__ A, const u16* __restrict__ BTh,
    const u16* __restrict__ BTg, const float* __restrict__ bias,
    u16* __restrict__ out)
{
  __shared__ u16 As[128 * 64];
  __shared__ u16 Bhs[128 * 64];
  __shared__ u16 Bgs[128 * 64];

  const int tid = threadIdx.x;
  const int wave = tid >> 6, lane = tid & 63;
  const int wm = wave >> 1, wn = wave & 1;
  const int qi = lane & 15, g = lane >> 4;

  // 2-D XCD ownership: XCD (cm,cn) in 2x4 owns a 16m x 8n tile rectangle.
  const int orig = blockIdx.y * gridDim.x + blockIdx.x;   // 1024 blocks
  const int c = orig & 7, j = orig >> 3;
  const int cm = c >> 2, cn = c & 3;
  const int jm = j & 15, jn = j >> 4;
  const int m0 = (cm * 16 + jm) << 7;
  const int n0 = (cn * 8 + jn) << 7;
  const int K = 1024;

  const int r0 = tid >> 3;
  const int scol = (((tid & 7) ^ ((tid >> 3) & 7)) << 3);
  const int swb = wave << 6;

  f32x4 acch[4][4], accg[4][4];
#pragma unroll
  for (int i = 0; i < 4; ++i)
#pragma unroll
    for (int j2 = 0; j2 < 4; ++j2) {
      acch[i][j2] = (f32x4){0.f, 0.f, 0.f, 0.f};
      accg[i][j2] = (f32x4){0.f, 0.f, 0.f, 0.f};
    }

  for (int t = 0; t < 16; ++t) {
    if (t) __syncthreads();
#pragma unroll
    for (int i = 0; i < 4; ++i) {
      const int r = i * 32 + r0;
      gload16(A + (size_t)(m0 + r) * K + t * 64 + scol,
              &As[(i * 256 + swb) * 8]);
    }
#pragma unroll
    for (int i = 0; i < 4; ++i) {
      const int r = i * 32 + r0;
      gload16(BTh + (size_t)(n0 + r) * K + t * 64 + scol,
              &Bhs[(i * 256 + swb) * 8]);
    }
#pragma unroll
    for (int i = 0; i < 4; ++i) {
      const int r = i * 32 + r0;
      gload16(BTg + (size_t)(n0 + r) * K + t * 64 + scol,
              &Bgs[(i * 256 + swb) * 8]);
    }
    __syncthreads();

    bf16x8 af[4][2], bfr[4][2];
#pragma unroll
    for (int mi = 0; mi < 4; ++mi)
#pragma unroll
      for (int kk = 0; kk < 2; ++kk) {
        const int row = wm * 64 + mi * 16 + qi;
        const int cb = ((kk * 64 + (g << 4)) ^ ((qi & 7) << 4));
        af[mi][kk] = *(const bf16x8*)((const char*)&As[0] + row * 128 + cb);
      }
    // ---- h half ----
#pragma unroll
    for (int ni = 0; ni < 4; ++ni)
#pragma unroll
      for (int kk = 0; kk < 2; ++kk) {
        const int row = wn * 64 + ni * 16 + qi;
        const int cb = ((kk * 64 + (g << 4)) ^ ((qi & 7) << 4));
        bfr[ni][kk] = *(const bf16x8*)((const char*)&Bhs[0] + row * 128 + cb);
      }
#pragma unroll
    for (int mi = 0; mi < 4; ++mi)
#pragma unroll
      for (int ni = 0; ni < 4; ++ni)
#pragma unroll
        for (int kk = 0; kk < 2; ++kk)
          acch[mi][ni] = mfma16(af[mi][kk], bfr[ni][kk], acch[mi][ni]);
    // ---- gate half (bfr reused) ----
#pragma unroll
    for (int ni = 0; ni < 4; ++ni)
#pragma unroll
      for (int kk = 0; kk < 2; ++kk) {
        const int row = wn * 64 + ni * 16 + qi;
        const int cb = ((kk * 64 + (g << 4)) ^ ((qi & 7) << 4));
        bfr[ni][kk] = *(const bf16x8*)((const char*)&Bgs[0] + row * 128 + cb);
      }
#pragma unroll
    for (int mi = 0; mi < 4; ++mi)
#pragma unroll
      for (int ni = 0; ni < 4; ++ni)
#pragma unroll
        for (int kk = 0; kk < 2; ++kk)
          accg[mi][ni] = mfma16(af[mi][kk], bfr[ni][kk], accg[mi][ni]);
  }

#pragma unroll
  for (int mi = 0; mi < 4; ++mi) {
#pragma unroll
    for (int ni = 0; ni < 4; ++ni) {
#pragma unroll
      for (int r = 0; r < 4; ++r) {
        const int m = m0 + wm * 64 + mi * 16 + g * 4 + r;
        const int n = n0 + wn * 64 + ni * 16 + qi;
        const float hv = acch[mi][ni][r] + bias[n];
        const float gv = accg[mi][ni][r] + bias[FF_ + n];
        out[(size_t)m * FF_ + n] = f2bf(hv * gelu_exact(gv));
      }
    }
  }
}

// ---------------------------------------------------------------------------
// Flash attention. Q pre-scaled by 0.125. Fixed-max softmax. 4 waves x 16 q.
// K/V staged direct-to-LDS via global_load_lds (T2 both-sides swizzle).
// ---------------------------------------------------------------------------
template<bool MASKED>
__global__ __launch_bounds__(256, 4) void attn_kernel(
    const u16* __restrict__ Q, const u16* __restrict__ Kb,
    const u16* __restrict__ VT, const float* __restrict__ bias,
    u16* __restrict__ O, int S, int T)
{
  __shared__ u16 Ks[64 * 64];        // [t][dh] stride 64, T2-swizzled
  __shared__ u16 VTs[64 * 64];       // [dh][t] stride 64, T2-swizzled
  __shared__ u16 Ps[4][16 * 72];     // per-wave P^T [q][t] (padded)
  __shared__ float biasS[64];

  const int bh = blockIdx.y;
  const int b = bh >> 4, h = bh & 15;
  const int tid = threadIdx.x;
  const int wave = tid >> 6, lane = tid & 63;
  const int g = lane >> 4, qi = lane & 15;
  const int q0w = blockIdx.x * 64 + wave * 16;

  const u16* Qb = Q + (size_t)bh * S * DH_;
  const u16* Kg = Kb + (size_t)bh * T * DH_;
  const u16* Vg = VT + (size_t)bh * DH_ * T;

  const int r0 = tid >> 3;
  const int scol = (((tid & 7) ^ ((tid >> 3) & 7)) << 3);
  const int swb = wave << 6;

  bf16x8 qf[2];
  qf[0] = *(const bf16x8*)&Qb[(q0w + qi) * DH_ + g * 8];
  qf[1] = *(const bf16x8*)&Qb[(q0w + qi) * DH_ + 32 + g * 8];

  f32x4 acc[4];
#pragma unroll
  for (int i = 0; i < 4; ++i) acc[i] = (f32x4){0.f, 0.f, 0.f, 0.f};
  float l_run = 1e-30f;

  u16* Pw = &Ps[wave][0];

  for (int t0 = 0; t0 < T; t0 += 64) {
    __syncthreads();
#pragma unroll
    for (int i = 0; i < 2; ++i) {
      const int r = i * 32 + r0;
      gload16(Kg + (size_t)(t0 + r) * DH_ + scol, &Ks[(i * 256 + swb) * 8]);
      gload16(Vg + (size_t)r * T + t0 + scol, &VTs[(i * 256 + swb) * 8]);
    }
    if (MASKED && tid < 64) biasS[tid] = bias[b * T + t0 + tid];
    __syncthreads();

    f32x4 sacc[4];
#pragma unroll
    for (int nt = 0; nt < 4; ++nt) sacc[nt] = (f32x4){0.f, 0.f, 0.f, 0.f};
#pragma unroll
    for (int kk = 0; kk < 2; ++kk) {
#pragma unroll
      for (int nt = 0; nt < 4; ++nt) {
        const int row = nt * 16 + qi;
        const int cb = ((kk * 64 + (g << 4)) ^ ((qi & 7) << 4));
        bf16x8 kf = *(const bf16x8*)((const char*)&Ks[0] + row * 128 + cb);
        sacc[nt] = mfma16(kf, qf[kk], sacc[nt]);
      }
    }
    float p[4][4];
    float lsum = 0.f;
#pragma unroll
    for (int nt = 0; nt < 4; ++nt)
#pragma unroll
      for (int r = 0; r < 4; ++r) {
        float v = sacc[nt][r];
        if (MASKED) v += biasS[nt * 16 + g * 4 + r];
        const float e = __expf(v);
        p[nt][r] = e;
        lsum += e;
      }
    lsum += __shfl_xor(lsum, 16);
    lsum += __shfl_xor(lsum, 32);
    l_run += lsum;

#pragma unroll
    for (int nt = 0; nt < 4; ++nt) {
      uint2 w;
      w.x = packbf2(p[nt][0], p[nt][1]);
      w.y = packbf2(p[nt][2], p[nt][3]);
      *(uint2*)&Pw[qi * 72 + nt * 16 + g * 4] = w;
    }

#pragma unroll
    for (int kk = 0; kk < 2; ++kk) {
      bf16x8 pf = *(const bf16x8*)&Pw[qi * 72 + kk * 32 + g * 8];
#pragma unroll
      for (int ndh = 0; ndh < 4; ++ndh) {
        const int row = ndh * 16 + qi;
        const int cb = ((kk * 64 + (g << 4)) ^ ((qi & 7) << 4));
        bf16x8 vf = *(const bf16x8*)((const char*)&VTs[0] + row * 128 + cb);
        acc[ndh] = mfma16(vf, pf, acc[ndh]);
      }
    }
  }

  const float inv = 1.f / l_run;
  const int qg = q0w + qi;
#pragma unroll
  for (int ndh = 0; ndh < 4; ++ndh) {
    uint2 w;
    w.x = packbf2(acc[ndh][0] * inv, acc[ndh][1] * inv);
    w.y = packbf2(acc[ndh][2] * inv, acc[ndh][3] * inv);
    *(uint2*)&O[(size_t)(b * S_ + qg) * D_ + h * DH_ + ndh * 16 + g * 4] = w;
  }
}

// ---------------------------------------------------------------------------
__global__ __launch_bounds__(256) void ln_kernel(
    const float* __restrict__ x, const float* __restrict__ gg,
    const float* __restrict__ bb, u16* __restrict__ out)
{
  __shared__ float red[8];
  const int row = blockIdx.x, tid = threadIdx.x;
  const float4 v = ((const float4*)(x + (size_t)row * D_))[tid];
  float s = v.x + v.y + v.z + v.w;
  float sq = v.x * v.x + v.y * v.y + v.z * v.z + v.w * v.w;
#pragma unroll
  for (int m = 32; m; m >>= 1) {
    s += __shfl_xor(s, m);
    sq += __shfl_xor(sq, m);
  }
  const int wave = tid >> 6, lane = tid & 63;
  if (lane == 0) { red[wave * 2] = s; red[wave * 2 + 1] = sq; }
  __syncthreads();
  const float St = red[0] + red[2] + red[4] + red[6];
  const float SQt = red[1] + red[3] + red[5] + red[7];
  const float mean = St * (1.f / 1024.f);
  float var = SQt * (1.f / 1024.f) - mean * mean;
  var = fmaxf(var, 0.f);
  const float rinv = rsqrtf(var + 1e-12f);
  const float4 g4 = ((const float4*)gg)[tid];
  const float4 b4 = ((const float4*)bb)[tid];
  uint2 o;
  o.x = packbf2((v.x - mean) * rinv * g4.x + b4.x, (v.y - mean) * rinv * g4.y + b4.y);
  o.y = packbf2((v.z - mean) * rinv * g4.z + b4.z, (v.w - mean) * rinv * g4.w + b4.w);
  ((uint2*)(out + (size_t)row * D_))[tid] = o;
}

__global__ __launch_bounds__(256) void transpose_w(
    const float* __restrict__ in, u16* __restrict__ out, int K, int N)
{
  __shared__ float tile[32][33];
  const int tx = threadIdx.x & 31, ty = threadIdx.x >> 5;
  const int k0 = blockIdx.y * 32, n0 = blockIdx.x * 32;
#pragma unroll
  for (int j = 0; j < 4; ++j)
    tile[ty + 8 * j][tx] = in[(size_t)(k0 + ty + 8 * j) * N + n0 + tx];
  __syncthreads();
#pragma unroll
  for (int j = 0; j < 4; ++j)
    out[(size_t)(n0 + ty + 8 * j) * K + k0 + tx] = f2bf(tile[tx][ty + 8 * j]);
}

__global__ __launch_bounds__(256) void transpose_w8(
    const float* __restrict__ w0, const float* __restrict__ w1,
    const float* __restrict__ w2, const float* __restrict__ w3,
    const float* __restrict__ w4, const float* __restrict__ w5,
    const float* __restrict__ w6, const float* __restrict__ w7,
    u16* __restrict__ outbase)
{
  __shared__ float tile[32][33];
  const float* srcs[8] = {w0, w1, w2, w3, w4, w5, w6, w7};
  const float* in = srcs[blockIdx.z];
  u16* out = outbase + (size_t)blockIdx.z * 1024 * 1024;
  const int tx = threadIdx.x & 31, ty = threadIdx.x >> 5;
  const int k0 = blockIdx.y * 32, n0 = blockIdx.x * 32;
#pragma unroll
  for (int j = 0; j < 4; ++j)
    tile[ty + 8 * j][tx] = in[(size_t)(k0 + ty + 8 * j) * 1024 + n0 + tx];
  __syncthreads();
#pragma unroll
  for (int j = 0; j < 4; ++j)
    out[(size_t)(n0 + ty + 8 * j) * 1024 + k0 + tx] = f2bf(tile[tx][ty + 8 * j]);
}

__global__ __launch_bounds__(256) void transpose_v(
    const u16* __restrict__ in, u16* __restrict__ out, int T)
{
  __shared__ u16 tile[32][33];
  const int tx = threadIdx.x & 31, ty = threadIdx.x >> 5;
  const int bh = blockIdx.z;
  const int t0 = blockIdx.x * 32, d0 = blockIdx.y * 32;
  const u16* ib = in + (size_t)bh * T * DH_;
  u16* ob = out + (size_t)bh * DH_ * T;
#pragma unroll
  for (int j = 0; j < 4; ++j)
    tile[ty + 8 * j][tx] = ib[(size_t)(t0 + ty + 8 * j) * DH_ + d0 + tx];
  __syncthreads();
#pragma unroll
  for (int j = 0; j < 4; ++j)
    ob[(size_t)(d0 + ty + 8 * j) * T + t0 + tx] = tile[tx][ty + 8 * j];
}

__global__ void cvt_bf16(const float* __restrict__ in, u16* __restrict__ out, int n4)
{
  const int i = blockIdx.x * blockDim.x + threadIdx.x;
  if (i < n4) {
    const float4 v = ((const float4*)in)[i];
    uint2 o;
    o.x = packbf2(v.x, v.y);
    o.y = packbf2(v.z, v.w);
    ((uint2*)out)[i] = o;
  }
}

__global__ void mask_bias(const int* __restrict__ mask, float* __restrict__ bias, int n)
{
  const int i = blockIdx.x * blockDim.x + threadIdx.x;
  if (i < n) bias[i] = mask[i] ? 0.f : -1e30f;
}

// ---------------------------------------------------------------------------
extern "C" void kernel_launch(void* const* d_in, const int* in_sizes, int n_in,
                              void* d_out, int out_size, void* d_ws, size_t ws_size,
                              hipStream_t stream)
{
  (void)in_sizes; (void)n_in; (void)out_size; (void)ws_size;
  const float* hidden = (const float*)d_in[0];
  const float* ctx    = (const float*)d_in[1];
  const int*   mask   = (const int*)d_in[2];
  const float* g1 = (const float*)d_in[3];
  const float* b1 = (const float*)d_in[4];
  const float* g2 = (const float*)d_in[5];
  const float* b2 = (const float*)d_in[6];
  const float* g3 = (const float*)d_in[7];
  const float* b3 = (const float*)d_in[8];
  const float* Wq1 = (const float*)d_in[9];
  const float* Wk1 = (const float*)d_in[10];
  const float* Wv1 = (const float*)d_in[11];
  const float* Wo1 = (const float*)d_in[12];
  const float* bo1 = (const float*)d_in[13];
  const float* Wq2 = (const float*)d_in[14];
  const float* Wk2 = (const float*)d_in[15];
  const float* Wv2 = (const float*)d_in[16];
  const float* Wo2 = (const float*)d_in[17];
  const float* bo2 = (const float*)d_in[18];
  const float* Wff1 = (const float*)d_in[19];
  const float* bff1 = (const float*)d_in[20];
  const float* Wff2 = (const float*)d_in[21];
  const float* bff2 = (const float*)d_in[22];

  char* ws = (char*)d_ws;
  size_t off = 0;
  auto alloc = [&](size_t bytes) -> void* {
    void* p = ws + off;
    off += (bytes + 255) & ~(size_t)255;
    return p;
  };
  // WqT1..WoT2: 8 CONTIGUOUS 2MB blocks (transpose_w8 target).
  u16* WqT1  = (u16*)alloc((size_t)1024 * 1024 * 2);
  u16* WkT1  = (u16*)alloc((size_t)1024 * 1024 * 2);
  u16* WvT1  = (u16*)alloc((size_t)1024 * 1024 * 2);
  u16* WoT1  = (u16*)alloc((size_t)1024 * 1024 * 2);
  u16* WqT2  = (u16*)alloc((size_t)1024 * 1024 * 2);
  u16* WkT2  = (u16*)alloc((size_t)1024 * 1024 * 2);
  u16* WvT2  = (u16*)alloc((size_t)1024 * 1024 * 2);
  u16* WoT2  = (u16*)alloc((size_t)1024 * 1024 * 2);
  u16* Wff1T = (u16*)alloc((size_t)8192 * 1024 * 2);
  u16* Wff2T = (u16*)alloc((size_t)1024 * 4096 * 2);
  u16* nbuf  = (u16*)alloc((size_t)M_ * D_ * 2);
  u16* hgbuf = (u16*)alloc((size_t)M_ * FF_ * 2);
  u16* qbuf  = (u16*)alloc((size_t)M_ * D_ * 2);
  u16* kbuf  = (u16*)alloc((size_t)M_ * D_ * 2);
  u16* vbuf  = (u16*)alloc((size_t)M_ * D_ * 2);
  u16* vtbuf = (u16*)alloc((size_t)M_ * D_ * 2);
  u16* attnb = (u16*)alloc((size_t)M_ * D_ * 2);
  u16* ctxb  = (u16*)alloc((size_t)M_ * D_ * 2);
  float* biasw = (float*)alloc((size_t)B_ * S_ * 4);
  float* hres = (float*)d_out;   // residual chain lives in d_out (f32)
  (void)WkT1; (void)WvT1; (void)WvT2; (void)WoT2;

  const dim3 blk(256);
  const dim3 gW8(32, 32, 8);
  const dim3 gQKV(24, 32);       // N=3072 -> 768 blocks
  const dim3 gQKV2(768);         // fused Q2 + KV2
  const dim3 gP(8, 32);          // N=1024 -> 256 blocks (direct)
  const dim3 gFF(32, 32);        // merged GEGLU: 1024 blocks
  const dim3 gA(16, 64);
  const dim3 gV(32, 2, 64);

  // weight prep (batched)
  transpose_w8<<<gW8, blk, 0, stream>>>(Wq1, Wk1, Wv1, Wo1, Wq2, Wk2, Wv2, Wo2,
                                        WqT1);
  transpose_w<<<dim3(256, 32), blk, 0, stream>>>(Wff1, Wff1T, 1024, 8192);
  transpose_w<<<dim3(32, 128), blk, 0, stream>>>(Wff2, Wff2T, 4096, 1024);
  cvt_bf16<<<dim3(4096), blk, 0, stream>>>(ctx, ctxb, 1048576);
  mask_bias<<<dim3(16), blk, 0, stream>>>(mask, biasw, B_ * S_);

  // --- self attention ---
  ln_kernel<<<dim3(M_), blk, 0, stream>>>(hidden, g1, b1, nbuf);
  gemm128<0><<<gQKV, blk, 0, stream>>>(nbuf, WqT1, nullptr, nullptr,
                                       qbuf, M_, 3072, 1024, 16);
  transpose_v<<<gV, blk, 0, stream>>>(vbuf, vtbuf, 1024);
  attn_kernel<false><<<gA, blk, 0, stream>>>(qbuf, kbuf, vtbuf, nullptr, attnb,
                                             S_, S_);
  // h1 = hidden + attnO + bo1 (direct, f32 into d_out)
  gemm128<1><<<gP, blk, 0, stream>>>(attnb, WoT1, bo1, hidden,
                                     hres, M_, 1024, 1024, 16);
  ln_kernel<<<dim3(M_), blk, 0, stream>>>(hres, g2, b2, nbuf);

  // --- cross attention ---
  // fused: blocks 0..255 Q2 (scaled) -> qbuf; 256..767 K2/V2 -> kbuf/vbuf
  qkv2_fused<<<gQKV2, blk, 0, stream>>>(nbuf, WqT2, ctxb, WkT2, qbuf, kbuf);
  transpose_v<<<gV, blk, 0, stream>>>(vbuf, vtbuf, 1024);
  attn_kernel<true><<<gA, blk, 0, stream>>>(qbuf, kbuf, vtbuf, biasw, attnb,
                                            S_, S_);
  // h2 = h1 + attnO + bo2 (in-place on d_out; elementwise-safe)
  gemm128<1><<<gP, blk, 0, stream>>>(attnb, WoT2, bo2, hres,
                                     hres, M_, 1024, 1024, 16);
  ln_kernel<<<dim3(M_), blk, 0, stream>>>(hres, g3, b3, nbuf);

  // --- GEGLU FF ---
  ffgeglu<<<gFF, blk, 0, stream>>>(nbuf, Wff1T, Wff1T + (size_t)FF_ * 1024,
                                   bff1, hgbuf);
  // out = h2 + (hg @ Wff2) + bff2 (direct, in-place on d_out)
  gemm128<1><<<gP, blk, 0, stream>>>(hgbuf, Wff2T, bff2, hres,
                                     hres, M_, 1024, 4096, 64);
}